// Round 10
// baseline (1409.835 us; speedup 1.0000x reference)
//
// LunarisCodex MoE-GPT forward, MI355X/gfx950. Round 10: logits GEMM at BK=32
// with 3x24KB buffers => 72KB LDS => 2 blocks/CU (cross-block stall coverage),
// re-derived 2-way-free swizzle for 64B row stride, nontemporal C-stores.
#include <hip/hip_runtime.h>

typedef __attribute__((ext_vector_type(8))) _Float16 half8;
typedef __attribute__((ext_vector_type(4))) float f32x4;

constexpr int Bc = 2, Tc = 1024, Dc = 768, NHc = 12, HDc = 64;
constexpr int Vc = 50257, Lc = 2, Ec = 8, Hc = 2048;
constexpr int Ntok = Bc * Tc;            // 2048
constexpr int CAPc = 320, CAPPc = 384;   // capacity, padded rows per expert
constexpr long long LOGITS_N = (long long)Bc * Tc * Vc;  // 102926336

typedef const __attribute__((address_space(1))) unsigned int* gas_t;
typedef __attribute__((address_space(3))) unsigned int* las_t;
__device__ __forceinline__ void gload16(const void* g, void* l) {
  __builtin_amdgcn_global_load_lds((gas_t)g, (las_t)l, 16, 0, 0);
}

__device__ __forceinline__ void splitf16(float a, unsigned short& h, unsigned short& l) {
  _Float16 hh = (_Float16)a;                       // RNE
  _Float16 ll = (_Float16)(a - (float)hh);
  h = __builtin_bit_cast(unsigned short, hh);
  l = __builtin_bit_cast(unsigned short, ll);
}
__device__ __forceinline__ unsigned short f16o(float a) {
  _Float16 hh = (_Float16)a;
  return __builtin_bit_cast(unsigned short, hh);
}

// ---------------- small kernels ----------------

__global__ void zero_small(float* psum, float* z2) {
  int t = threadIdx.x;
  if (t < Lc * Ec) psum[t] = 0.f;
  if (t < Lc) z2[t] = 0.f;
}

// embed: x (f32) + x16 (split-fp16 [hi768|lo768])
__global__ void embed_k(const int* __restrict__ idx, const float* __restrict__ wte,
                        float* __restrict__ x, unsigned short* __restrict__ x16) {
  int n = blockIdx.x;
  long long v = idx[n];
  const float4* src = (const float4*)(wte + v * 768);
  float4* dst = (float4*)(x + (long long)n * 768);
  int t = threadIdx.x;
  if (t < 192) {
    float4 val = src[t];
    dst[t] = val;
    ushort4 h, l;
    splitf16(val.x, h.x, l.x); splitf16(val.y, h.y, l.y);
    splitf16(val.z, h.z, l.z); splitf16(val.w, h.w, l.w);
    unsigned short* d = x16 + (long long)n * 1536 + t * 4;
    *(ushort4*)d = h;
    *(ushort4*)(d + 768) = l;
  }
}

// f32 -> fp16 single (for wte)
__global__ void f2h4(const float* __restrict__ in, unsigned short* __restrict__ out,
                     long long n4) {
  long long i = (long long)blockIdx.x * 256 + threadIdx.x;
  if (i >= n4) return;
  float4 v = ((const float4*)in)[i];
  ushort4 o;
  o.x = f16o(v.x); o.y = f16o(v.y); o.z = f16o(v.z); o.w = f16o(v.w);
  ((ushort4*)out)[i] = o;
}

// f32 weights (K,N) -> fp16 transposed. SP=1: (N,2K) [hi|lo]; SP=0: (N,K).
// ILV=1: dst row remapped for g/u interleave: n' = (h>>4)*32 + is_u*16 + (h&15),
// h = n&2047, is_u = n>>11 (requires N=4096).
template <int SP, int ILV>
__global__ void __launch_bounds__(256) split2_wT(const float* __restrict__ src,
    unsigned short* __restrict__ dst, int K, int N, long long sS, long long sD) {
  __shared__ float t[32][33];
  int z = blockIdx.z;
  src += (long long)z * sS;
  dst += (long long)z * sD;
  int n0 = blockIdx.x * 32, k0 = blockIdx.y * 32;
  int tid = threadIdx.x;
  int r = tid >> 3, c4 = (tid & 7) * 4;
  float4 v = *(const float4*)(src + (long long)(k0 + r) * N + n0 + c4);
  t[r][c4 + 0] = v.x; t[r][c4 + 1] = v.y; t[r][c4 + 2] = v.z; t[r][c4 + 3] = v.w;
  __syncthreads();
  int n = tid >> 3, kq = (tid & 7) * 4;
  ushort4 h, l;
  splitf16(t[kq + 0][n], h.x, l.x);
  splitf16(t[kq + 1][n], h.y, l.y);
  splitf16(t[kq + 2][n], h.z, l.z);
  splitf16(t[kq + 3][n], h.w, l.w);
  const int lda = SP ? 2 * K : K;
  int nd = n0 + n;
  if (ILV) {
    int hh = nd & 2047, iu = nd >> 11;
    nd = ((hh >> 4) << 5) + (iu << 4) + (hh & 15);
  }
  unsigned short* d = dst + (long long)nd * lda + k0 + kq;
  *(ushort4*)d = h;
  if (SP) *(ushort4*)(d + K) = l;
}

// rmsnorm over 768 cols; strided in/out, f32 out
__global__ void __launch_bounds__(256) rmsnorm_k(const float* in, int istride,
                                                 float* outp, int ostride,
                                                 const float* w) {
  long long n = blockIdx.x;
  const float* xr = in + n * istride;
  float* yr = outp + n * ostride;
  int tid = threadIdx.x;
  float s = 0.f;
  for (int i = tid; i < 768; i += 256) { float v = xr[i]; s += v * v; }
  #pragma unroll
  for (int o = 32; o; o >>= 1) s += __shfl_down(s, o);
  __shared__ float red[4];
  __shared__ float bs;
  if ((tid & 63) == 0) red[tid >> 6] = s;
  __syncthreads();
  if (tid == 0) bs = rsqrtf((red[0] + red[1] + red[2] + red[3]) / 768.0f + 1e-5f);
  __syncthreads();
  float sc = bs;
  for (int i = tid; i < 768; i += 256) yr[i] = xr[i] * sc * w[i];
}

// rmsnorm -> fp16 single output (final ln before logits)
__global__ void __launch_bounds__(256) rmsnorm_h(const float* in,
                                                 unsigned short* outp, const float* w) {
  long long n = blockIdx.x;
  const float* xr = in + n * 768;
  unsigned short* yr = outp + n * 768;
  int tid = threadIdx.x;
  float s = 0.f;
  for (int i = tid; i < 768; i += 256) { float v = xr[i]; s += v * v; }
  #pragma unroll
  for (int o = 32; o; o >>= 1) s += __shfl_down(s, o);
  __shared__ float red[4];
  __shared__ float bs;
  if ((tid & 63) == 0) red[tid >> 6] = s;
  __syncthreads();
  if (tid == 0) bs = rsqrtf((red[0] + red[1] + red[2] + red[3]) / 768.0f + 1e-5f);
  __syncthreads();
  float sc = bs;
  for (int i = tid; i < 768; i += 256) yr[i] = f16o(xr[i] * sc * w[i]);
}

// fused q/k rmsnorm + RoPE + V transpose. One block per token.
__global__ void __launch_bounds__(256) qk_rope(const float* __restrict__ qkv,
    const float* __restrict__ qnw, const float* __restrict__ knw,
    unsigned short* __restrict__ qr, unsigned short* __restrict__ kr,
    unsigned short* __restrict__ vr) {
  int n = blockIdx.x;
  int t = n & 1023, b = n >> 10;
  const float* row = qkv + (long long)n * 2304;
  int tid = threadIdx.x;
  float sq = 0.f, sk = 0.f;
  for (int i = tid; i < 768; i += 256) {
    float q = row[i]; sq += q * q;
    float k = row[768 + i]; sk += k * k;
  }
  #pragma unroll
  for (int o = 32; o; o >>= 1) { sq += __shfl_down(sq, o); sk += __shfl_down(sk, o); }
  __shared__ float redq[4], redk[4];
  __shared__ float bq, bk;
  if ((tid & 63) == 0) { redq[tid >> 6] = sq; redk[tid >> 6] = sk; }
  __syncthreads();
  if (tid == 0) {
    bq = rsqrtf((redq[0] + redq[1] + redq[2] + redq[3]) / 768.0f + 1e-5f);
    bk = rsqrtf((redk[0] + redk[1] + redk[2] + redk[3]) / 768.0f + 1e-5f);
  }
  __syncthreads();
  float nq = bq, nk = bk;
  for (int i = tid; i < 384; i += 256) {
    int hh = i >> 5, j = i & 31;
    int c = hh * 64 + 2 * j;
    float ang = (float)t * powf(10000.0f, -((float)j * (1.0f / 32.0f)));
    float cs = cosf(ang), sn = sinf(ang);
    int z = b * 12 + hh;
    long long qb = ((long long)z * 1024 + t) * 128 + 2 * j;
    unsigned short h0, l0, h1, l1;
    float q0 = row[c] * nq * qnw[c], q1 = row[c + 1] * nq * qnw[c + 1];
    splitf16(q0 * cs - q1 * sn, h0, l0);
    splitf16(q0 * sn + q1 * cs, h1, l1);
    *(unsigned int*)&qr[qb] = (unsigned)h0 | ((unsigned)h1 << 16);
    *(unsigned int*)&qr[qb + 64] = (unsigned)l0 | ((unsigned)l1 << 16);
    float k0 = row[768 + c] * nk * knw[c], k1 = row[768 + c + 1] * nk * knw[c + 1];
    splitf16(k0 * cs - k1 * sn, h0, l0);
    splitf16(k0 * sn + k1 * cs, h1, l1);
    *(unsigned int*)&kr[qb] = (unsigned)h0 | ((unsigned)h1 << 16);
    *(unsigned int*)&kr[qb + 64] = (unsigned)l0 | ((unsigned)l1 << 16);
    splitf16(row[1536 + c], h0, l0);
    splitf16(row[1536 + c + 1], h1, l1);
    long long vb = ((long long)z * 64 + 2 * j) * 2048 + t;
    vr[vb] = h0; vr[vb + 1024] = l0;
    vr[vb + 2048] = h1; vr[vb + 3072] = l1;
  }
}

// ---------------- fused flash attention ----------------
__global__ void __launch_bounds__(256) flash_attn(
    const unsigned short* __restrict__ qr, const unsigned short* __restrict__ kr,
    const unsigned short* __restrict__ vr, unsigned short* __restrict__ yout) {
  __shared__ __align__(16) unsigned short Ph[4][16][72];
  __shared__ __align__(16) unsigned short Pl[4][16][72];
  int bid = blockIdx.x;
  int z = bid >> 4;
  int qt = 15 - (bid & 15);          // heavy tiles first (load balance)
  int b = z / 12, h = z % 12;
  int q0 = qt * 64;
  int wave = threadIdx.x >> 6, lane = threadIdx.x & 63;
  int lr = lane & 15, lg = lane >> 4;
  int qw = q0 + wave * 16;           // this wave's 16 q rows
  half8 af[2][2];
  const unsigned short* qbase = qr + ((long long)z * 1024 + qw + lr) * 128;
  #pragma unroll
  for (int ks = 0; ks < 2; ++ks)
    #pragma unroll
    for (int p = 0; p < 2; ++p)
      af[ks][p] = *(const half8*)(qbase + p * 64 + ks * 32 + lg * 8);
  f32x4 accy[4];
  #pragma unroll
  for (int df = 0; df < 4; ++df) accy[df] = (f32x4){0.f, 0.f, 0.f, 0.f};
  float mrun[4] = {-3.4e38f, -3.4e38f, -3.4e38f, -3.4e38f};
  float srun[4] = {0.f, 0.f, 0.f, 0.f};
  for (int kt = 0; kt <= qt; ++kt) {
    int kv0 = kt * 64;
    f32x4 s[4];
    #pragma unroll
    for (int nf = 0; nf < 4; ++nf) s[nf] = (f32x4){0.f, 0.f, 0.f, 0.f};
    const unsigned short* kbase = kr + ((long long)z * 1024 + kv0 + lr) * 128;
    #pragma unroll
    for (int nf = 0; nf < 4; ++nf) {
      const unsigned short* kb = kbase + nf * 16 * 128;
      #pragma unroll
      for (int ks = 0; ks < 2; ++ks) {
        half8 bh = *(const half8*)(kb + ks * 32 + lg * 8);
        half8 bl = *(const half8*)(kb + 64 + ks * 32 + lg * 8);
        s[nf] = __builtin_amdgcn_mfma_f32_16x16x32_f16(af[ks][0], bh, s[nf], 0, 0, 0);
        s[nf] = __builtin_amdgcn_mfma_f32_16x16x32_f16(af[ks][1], bh, s[nf], 0, 0, 0);
        s[nf] = __builtin_amdgcn_mfma_f32_16x16x32_f16(af[ks][0], bl, s[nf], 0, 0, 0);
      }
    }
    bool diag = (kt == qt);
    #pragma unroll
    for (int nf = 0; nf < 4; ++nf)
      #pragma unroll
      for (int j = 0; j < 4; ++j) {
        float v = s[nf][j] * 0.125f;
        if (diag && (nf * 16 + lr > wave * 16 + lg * 4 + j)) v = -1e30f;
        s[nf][j] = v;
      }
    #pragma unroll
    for (int j = 0; j < 4; ++j) {
      float tm = fmaxf(fmaxf(s[0][j], s[1][j]), fmaxf(s[2][j], s[3][j]));
      #pragma unroll
      for (int o = 1; o < 16; o <<= 1) tm = fmaxf(tm, __shfl_xor(tm, o));
      float mnew = fmaxf(mrun[j], tm);
      float sc = expf(mrun[j] - mnew);
      float ts = 0.f;
      #pragma unroll
      for (int nf = 0; nf < 4; ++nf) {
        float p = expf(s[nf][j] - mnew);
        ts += p;
        unsigned short ph, pl;
        splitf16(p, ph, pl);
        Ph[wave][lg * 4 + j][nf * 16 + lr] = ph;
        Pl[wave][lg * 4 + j][nf * 16 + lr] = pl;
      }
      #pragma unroll
      for (int o = 1; o < 16; o <<= 1) ts += __shfl_xor(ts, o);
      srun[j] = srun[j] * sc + ts;
      mrun[j] = mnew;
      #pragma unroll
      for (int df = 0; df < 4; ++df) accy[df][j] *= sc;
    }
    #pragma unroll
    for (int ks2 = 0; ks2 < 2; ++ks2) {
      half8 aph = *(const half8*)&Ph[wave][lr][ks2 * 32 + lg * 8];
      half8 apl = *(const half8*)&Pl[wave][lr][ks2 * 32 + lg * 8];
      #pragma unroll
      for (int df = 0; df < 4; ++df) {
        const unsigned short* vb =
            vr + ((long long)z * 64 + df * 16 + lr) * 2048 + kv0 + ks2 * 32 + lg * 8;
        half8 bvh = *(const half8*)vb;
        half8 bvl = *(const half8*)(vb + 1024);
        accy[df] = __builtin_amdgcn_mfma_f32_16x16x32_f16(aph, bvh, accy[df], 0, 0, 0);
        accy[df] = __builtin_amdgcn_mfma_f32_16x16x32_f16(apl, bvh, accy[df], 0, 0, 0);
        accy[df] = __builtin_amdgcn_mfma_f32_16x16x32_f16(aph, bvl, accy[df], 0, 0, 0);
      }
    }
  }
  float inv[4];
  #pragma unroll
  for (int j = 0; j < 4; ++j) inv[j] = 1.0f / srun[j];
  #pragma unroll
  for (int df = 0; df < 4; ++df)
    #pragma unroll
    for (int j = 0; j < 4; ++j) {
      long long tok = (long long)b * 1024 + qw + lg * 4 + j;
      int col = h * 64 + df * 16 + lr;
      unsigned short hh, ll;
      splitf16(accy[df][j] * inv[j], hh, ll);
      yout[tok * 1536 + col] = hh;
      yout[tok * 1536 + 768 + col] = ll;
    }
}

// gate: logits(f32), softmax probs, argmax (first-max), aux accumulators
__global__ void __launch_bounds__(256) gate_k(const float* __restrict__ xin,
    const float* __restrict__ gw, int* __restrict__ top,
    float* __restrict__ psum, float* __restrict__ z2) {
  __shared__ float gws[768 * 8];
  __shared__ float pacc[8];
  __shared__ float zacc;
  int tid = threadIdx.x;
  for (int i = tid; i < 768 * 8 / 4; i += 256) ((float4*)gws)[i] = ((const float4*)gw)[i];
  if (tid < 8) pacc[tid] = 0.f;
  if (tid == 0) zacc = 0.f;
  __syncthreads();
  int n = blockIdx.x * 256 + tid;
  const float4* xr4 = (const float4*)(xin + (long long)n * 768);
  float l[8] = {0, 0, 0, 0, 0, 0, 0, 0};
  for (int d4 = 0; d4 < 192; ++d4) {
    float4 xv = xr4[d4];
    const float* g = &gws[d4 * 32];
    #pragma unroll
    for (int e = 0; e < 8; ++e)
      l[e] += xv.x * g[e] + xv.y * g[8 + e] + xv.z * g[16 + e] + xv.w * g[24 + e];
  }
  float mx = l[0]; int bi = 0;
  #pragma unroll
  for (int e = 1; e < 8; ++e) if (l[e] > mx) { mx = l[e]; bi = e; }  // first-max
  float p[8]; float se = 0.f;
  #pragma unroll
  for (int e = 0; e < 8; ++e) { p[e] = expf(l[e] - mx); se += p[e]; }
  float z = mx + logf(se);
  top[n] = bi;
  #pragma unroll
  for (int e = 0; e < 8; ++e) atomicAdd(&pacc[e], p[e] / se);
  atomicAdd(&zacc, z * z);
  __syncthreads();
  if (tid < 8) atomicAdd(&psum[tid], pacc[tid]);
  if (tid == 0) atomicAdd(z2, zacc);
}

// single-wave rank scan (matches stable argsort arrival order)
__global__ void route_scan(const int* __restrict__ top, int* __restrict__ rank,
                           int* __restrict__ cnt) {
  int lane = threadIdx.x;
  int c[8] = {0, 0, 0, 0, 0, 0, 0, 0};
  unsigned long long below = (1ull << lane) - 1ull;
  for (int s = 0; s < Ntok / 64; ++s) {
    int n = s * 64 + lane;
    int e = top[n];
    int r = 0;
    #pragma unroll
    for (int q = 0; q < 8; ++q) {
      unsigned long long m = __ballot(e == q);
      if (e == q) r = c[q] + __popcll(m & below);
      c[q] += __popcll(m);
    }
    rank[n] = r;
  }
  #pragma unroll
  for (int q = 0; q < 8; ++q) if (lane == q) cnt[q] = c[q];
}

// ffn f32 -> xb16. SP=1: (row,1536=[hi|lo]); SP=0: (row,768) hi only.
template <int SP>
__global__ void scatter_xb(const float* __restrict__ xin, const int* __restrict__ top,
                           const int* __restrict__ rank, unsigned short* __restrict__ xb) {
  int n = blockIdx.x;
  int r = rank[n];
  if (r >= CAPc) return;
  int e = top[n];
  int t = threadIdx.x;
  if (t >= 192) return;
  float4 v = ((const float4*)(xin + (long long)n * 768))[t];
  ushort4 h, l;
  splitf16(v.x, h.x, l.x); splitf16(v.y, h.y, l.y);
  splitf16(v.z, h.z, l.z); splitf16(v.w, h.w, l.w);
  const int lda = SP ? 1536 : 768;
  unsigned short* dst = xb + ((long long)e * CAPPc + r) * lda + t * 4;
  *(ushort4*)dst = h;
  if (SP) *(ushort4*)(dst + 768) = l;
}

// h + expert-out -> x (f32) AND x16 (split-fp16) for next layer
__global__ void gather_add(const float* __restrict__ h, const float* __restrict__ yexp,
                           const int* __restrict__ top, const int* __restrict__ rank,
                           float* __restrict__ xo, unsigned short* __restrict__ x16) {
  int n = blockIdx.x;
  int r = rank[n], e = top[n];
  bool kept = r < CAPc;
  int rc = kept ? r : (CAPc - 1);
  const float4* hs = (const float4*)(h + (long long)n * 768);
  const float4* ys = (const float4*)(yexp + ((long long)e * CAPPc + rc) * 768);
  float4* dst = (float4*)(xo + (long long)n * 768);
  int t = threadIdx.x;
  if (t < 192) {
    float4 v = hs[t];
    if (kept) { float4 y = ys[t]; v.x += y.x; v.y += y.y; v.z += y.z; v.w += y.w; }
    dst[t] = v;
    ushort4 hh, ll;
    splitf16(v.x, hh.x, ll.x); splitf16(v.y, hh.y, ll.y);
    splitf16(v.z, hh.z, ll.z); splitf16(v.w, hh.w, ll.w);
    unsigned short* d = x16 + (long long)n * 1536 + t * 4;
    *(ushort4*)d = hh;
    *(ushort4*)(d + 768) = ll;
  }
}

__global__ void aux_fin(const float* __restrict__ psum, const int* __restrict__ cnt,
                        const float* __restrict__ z2, float* __restrict__ outp) {
  if (threadIdx.x == 0) {
    float aux = 0.f;
    for (int l = 0; l < Lc; ++l) {
      float bl = 0.f;
      for (int e = 0; e < 8; ++e)
        bl += (psum[l * 8 + e] * (1.0f / 2048.0f)) * ((float)cnt[l * 8 + e] * (1.0f / 2048.0f));
      aux += bl * (0.01f * 8.0f) + (z2[l] * (1.0f / 2048.0f)) * 0.001f;
    }
    outp[0] = aux;
  }
}

// ---------------- fp16 MFMA GEMM (single-barrier pipelined dbuf) ----------
// C(M,N) f32 [+Add] = A @ Bt^T. SPLIT=1: [hi K|lo K] (lda=2K), 3 MFMA terms per
// 32-k-slice (4 planes). SPLIT=0: lda=K, BK=64 (2 planes).
// SILU: 1 = silu(g)*u -> split-fp16 act (g/u-interleaved B, BN=128); 2 = single.
template <int BN, int SPLIT, int ADD, int NTAIL, int SILU>
__global__ void __launch_bounds__(256) gemm_h(
    const unsigned short* __restrict__ A, const unsigned short* __restrict__ Bt,
    float* __restrict__ C, const float* __restrict__ Add,
    int M, int N, int K, int ldc, int gx, int gy,
    long long sA, long long sB, int zdiv, long long sC1, long long sC2) {
  constexpr int FN = (BN == 128) ? 4 : 2;
  constexpr int APL = 128 * 32;            // A plane (shorts)
  constexpr int BPL = BN * 32;             // B plane (shorts)
  constexpr int BUF = 2 * APL + 2 * BPL;   // Ah|Al|Bh|Bl
  __shared__ __align__(16) unsigned short lds[2][BUF];
  int tot = gridDim.x;
  int lin = blockIdx.x;
  if ((tot & 7) == 0) lin = (lin & 7) * (tot >> 3) + (lin >> 3);  // XCD chunking
  int pz = lin / (gx * gy);
  int r2 = lin - pz * (gx * gy);
  const int m0 = (r2 % gx) * 128, n0 = (r2 / gx) * BN;
  A += (long long)pz * sA;
  Bt += (long long)pz * sB;
  const long long co = (long long)(pz / zdiv) * sC1 + (long long)(pz % zdiv) * sC2;
  const int lda = SPLIT ? 2 * K : K;
  const int NS = SPLIT ? K / 32 : K / 64;
  const int tid = threadIdx.x;
  const int lane = tid & 63, wave = tid >> 6;
  const int wm = (BN == 128) ? (wave >> 1) : (wave & 1);
  const int wn = (BN == 128) ? (wave & 1) : (wave >> 1);
  const int srow = tid >> 2, scol = (tid & 3) * 8;
  const unsigned short* Ar = A + (long long)(m0 + srow) * lda + scol;
  int br0 = n0 + srow;
  if (NTAIL) br0 = min(br0, N - 1);
  const unsigned short* Br = Bt + (long long)br0 * lda + scol;
  int br1 = n0 + srow + 64;
  if (NTAIL) br1 = min(br1, N - 1);
  const unsigned short* Br2 = Bt + (long long)br1 * lda + scol;

  auto STAGE = [&](int buf, int s) {
    const int kh = SPLIT ? s * 32 : s * 64;
    const int kl = SPLIT ? K + s * 32 : s * 64 + 32;
    unsigned short* L = lds[buf];
    gload16(Ar + kh, &L[wave * 512]);
    gload16(Ar + (long long)64 * lda + kh, &L[2048 + wave * 512]);
    gload16(Ar + kl, &L[APL + wave * 512]);
    gload16(Ar + (long long)64 * lda + kl, &L[APL + 2048 + wave * 512]);
    gload16(Br + kh, &L[2 * APL + wave * 512]);
    gload16(Br + kl, &L[2 * APL + BPL + wave * 512]);
    if (BN == 128) {
      gload16(Br2 + kh, &L[2 * APL + 2048 + wave * 512]);
      gload16(Br2 + kl, &L[2 * APL + BPL + 2048 + wave * 512]);
    }
  };

  f32x4 acc[4][FN];
  #pragma unroll
  for (int m = 0; m < 4; ++m)
    #pragma unroll
    for (int n = 0; n < FN; ++n) acc[m][n] = (f32x4){0.f, 0.f, 0.f, 0.f};

  STAGE(0, 0);
  int cur = 0;
  for (int s = 0; s < NS; ++s) {
    asm volatile("s_waitcnt vmcnt(0)" ::: "memory");   // own stage-s loads landed
    __builtin_amdgcn_sched_barrier(0);
    __builtin_amdgcn_s_barrier();   // all waves: stage-s in LDS; prev reads retired
    if (s + 1 < NS) STAGE(cur ^ 1, s + 1);   // overlaps with reads+MFMA below
    const unsigned short* L = lds[cur];
    half8 bfh[FN], bfl[FN];
    #pragma unroll
    for (int n = 0; n < FN; ++n) {
      int bo = (wn * (FN * 16) + n * 16 + (lane & 15)) * 32 + (lane >> 4) * 8;
      bfh[n] = *(const half8*)&L[2 * APL + bo];
      bfl[n] = *(const half8*)&L[2 * APL + BPL + bo];
    }
    __builtin_amdgcn_s_setprio(1);
    #pragma unroll
    for (int m = 0; m < 4; ++m) {
      int ao = (wm * 64 + m * 16 + (lane & 15)) * 32 + (lane >> 4) * 8;
      half8 afh = *(const half8*)&L[ao];
      half8 afl = *(const half8*)&L[APL + ao];
      #pragma unroll
      for (int n = 0; n < FN; ++n) {
        acc[m][n] = __builtin_amdgcn_mfma_f32_16x16x32_f16(afh, bfh[n], acc[m][n], 0, 0, 0);
        if (SPLIT) {
          acc[m][n] = __builtin_amdgcn_mfma_f32_16x16x32_f16(afl, bfh[n], acc[m][n], 0, 0, 0);
          acc[m][n] = __builtin_amdgcn_mfma_f32_16x16x32_f16(afh, bfl[n], acc[m][n], 0, 0, 0);
        } else {
          acc[m][n] = __builtin_amdgcn_mfma_f32_16x16x32_f16(afl, bfl[n], acc[m][n], 0, 0, 0);
        }
      }
    }
    __builtin_amdgcn_s_setprio(0);
    cur ^= 1;
  }
  if constexpr (SILU) {
    // g/u-interleaved cols: nf even = g, nf odd = u for the same 16-h block.
    unsigned short* act = (unsigned short*)C;
    #pragma unroll
    for (int m = 0; m < 4; ++m)
      #pragma unroll
      for (int p = 0; p < FN / 2; ++p) {
        f32x4 g = acc[m][2 * p], u = acc[m][2 * p + 1];
        int colh = ((n0 + wn * (FN * 16)) >> 1) + p * 16 + (lane & 15);
        #pragma unroll
        for (int j = 0; j < 4; ++j) {
          long long row = m0 + wm * 64 + m * 16 + (lane >> 4) * 4 + j;
          float gv = g[j];
          float a = gv / (1.f + expf(-gv)) * u[j];
          long long o = co + row * ldc + colh;
          if (SILU == 1) {
            unsigned short hh, ll;
            splitf16(a, hh, ll);
            act[o] = hh;
            act[o + 2048] = ll;
          } else {
            act[o] = f16o(a);
          }
        }
      }
  } else {
    #pragma unroll
    for (int m = 0; m < 4; ++m)
      #pragma unroll
      for (int n = 0; n < FN; ++n) {
        int col = n0 + wn * (FN * 16) + n * 16 + (lane & 15);
        if (!NTAIL || col < N) {
          #pragma unroll
          for (int j = 0; j < 4; ++j) {
            long long row = m0 + wm * 64 + m * 16 + (lane >> 4) * 4 + j;
            long long o = co + row * ldc + col;
            float v = acc[m][n][j];
            if (ADD) v += Add[o];
            C[o] = v;
          }
        }
      }
  }
}

// ---------------- logits GEMM: 256x128 tile, BK=32, 3x24KB bufs (72KB) ----
// 2 blocks/CU -> cross-block coverage of barrier/vmcnt stalls. Distance-2
// staging into buf[(s+2)%3]; ONE s_barrier per step; vmcnt(3) counted wait
// (LPS=3/thread: 2 A + 1 B). Swizzle for 64B row stride: blk ^= (row>>1)&3
// -> 16-row b128 frag spread across banks {0,4..28} x2 (2-way = free, m136).
// C written with nontemporal stores (412MB stream must not evict B panel).
__global__ void __launch_bounds__(512) gemm_logits(
    const unsigned short* __restrict__ A, const unsigned short* __restrict__ Bt,
    float* __restrict__ C, int M, int N, int K, int ldc, int gx) {
  constexpr int BUFS = 12288;            // shorts per buffer (24KB)
  constexpr int BOFF = 8192;             // B region offset (shorts): A = 256x32
  __shared__ __align__(16) unsigned short lds[3 * BUFS];   // 72KB
  int tot = gridDim.x;
  int lin = blockIdx.x;
  if ((tot & 7) == 0) lin = (lin & 7) * (tot >> 3) + (lin >> 3);  // XCD chunking
  const int m0 = (lin % gx) * 256, n0 = (lin / gx) * 128;
  const int tid = threadIdx.x;
  const int lane = tid & 63;
  const int wm = (tid >> 6) >> 1, wn = (tid >> 6) & 1;
  const int NS = K / 32;   // 24

  auto STAGE = [&](int buf, int t) {
    const int k0 = t * 32;
    unsigned short* L = lds + buf * BUFS;
    #pragma unroll
    for (int i = 0; i < 2; ++i) {                     // A: 256x32 = 1024 x 16B
      int idx = tid + i * 512;
      int row = idx >> 2, blk = idx & 3;
      gload16(A + (long long)(m0 + row) * K + k0 + ((blk ^ ((row >> 1) & 3)) << 3),
              L + idx * 8);
    }
    {                                                 // B: 128x32 = 512 x 16B
      int row = tid >> 2, blk = tid & 3;
      int br = min(n0 + row, N - 1);
      gload16(Bt + (long long)br * K + k0 + ((blk ^ ((row >> 1) & 3)) << 3),
              L + BOFF + tid * 8);
    }
  };

  f32x4 acc[4][4];
  #pragma unroll
  for (int mf = 0; mf < 4; ++mf)
    #pragma unroll
    for (int nf = 0; nf < 4; ++nf) acc[mf][nf] = (f32x4){0.f, 0.f, 0.f, 0.f};

  STAGE(0, 0); STAGE(1, 1);
  for (int s = 0; s < NS; ++s) {
    if (s + 1 < NS) asm volatile("s_waitcnt vmcnt(3)" ::: "memory");
    else            asm volatile("s_waitcnt vmcnt(0)" ::: "memory");
    __builtin_amdgcn_sched_barrier(0);
    __builtin_amdgcn_s_barrier();          // tile s ready; buf[(s+2)%3] released
    if (s + 2 < NS) STAGE((s + 2) % 3, s + 2);   // overlaps with reads+MFMA
    const unsigned short* L = lds + (s % 3) * BUFS;
    half8 a[4], b[4];
    #pragma unroll
    for (int mf = 0; mf < 4; ++mf) {
      int row = wm * 64 + mf * 16 + (lane & 15);
      int blk = (lane >> 4) ^ ((row >> 1) & 3);
      a[mf] = *(const half8*)(L + row * 32 + blk * 8);
    }
    #pragma unroll
    for (int nf = 0; nf < 4; ++nf) {
      int row = wn * 64 + nf * 16 + (lane & 15);
      int blk = (lane >> 4) ^ ((row >> 1) & 3);
      b[nf] = *(const half8*)(L + BOFF + row * 32 + blk * 8);
    }
    __builtin_amdgcn_s_setprio(1);
    #pragma unroll
    for (int mf = 0; mf < 4; ++mf)
      #pragma unroll
      for (int nf = 0; nf < 4; ++nf)
        acc[mf][nf] = __builtin_amdgcn_mfma_f32_16x16x32_f16(a[mf], b[nf],
                                                             acc[mf][nf], 0, 0, 0);
    __builtin_amdgcn_s_setprio(0);
  }
  #pragma unroll
  for (int mf = 0; mf < 4; ++mf)
    #pragma unroll
    for (int nf = 0; nf < 4; ++nf) {
      int col = n0 + wn * 64 + nf * 16 + (lane & 15);
      if (col < N) {
        #pragma unroll
        for (int j = 0; j < 4; ++j) {
          long long row = m0 + wm * 64 + mf * 16 + (lane >> 4) * 4 + j;
          __builtin_nontemporal_store(acc[mf][nf][j], &C[row * (long long)ldc + col]);
        }
      }
    }
}

// ---------------- host launch ----------------

extern "C" void kernel_launch(void* const* d_in, const int* in_sizes, int n_in,
                              void* d_out, int out_size, void* d_ws, size_t ws_size,
                              hipStream_t stream) {
  (void)in_sizes; (void)n_in; (void)out_size; (void)ws_size;
  const int*   idx   = (const int*)d_in[0];
  const float* wte   = (const float*)d_in[1];
  const float* wqkv  = (const float*)d_in[2];
  const float* qnw   = (const float*)d_in[3];
  const float* knw   = (const float*)d_in[4];
  const float* oproj = (const float*)d_in[5];
  const float* ffnw  = (const float*)d_in[6];
  const float* gatew = (const float*)d_in[7];
  const float* w13   = (const float*)d_in[8];
  const float* w2p   = (const float*)d_in[9];
  const float* lnf   = (const float*)d_in[10];
  float* out = (float*)d_out;

  char* base = (char*)d_ws;
  size_t off = 0;
  auto alloc = [&](size_t bytes) -> char* {
    off = (off + 255) & ~(size_t)255;
    char* p = base + off; off += bytes; return p;
  };
  float* x     = (float*)alloc((size_t)Ntok * 768 * 4);
  float* qkv   = (float*)alloc((size_t)Ntok * 2304 * 4);
  float* hbuf  = (float*)alloc((size_t)Ntok * 768 * 4);
  float* ffn   = (float*)alloc((size_t)Ntok * 768 * 4);
  unsigned short* x16   = (unsigned short*)alloc((size_t)Ntok * 1536 * 2);
  unsigned short* yfl16 = (unsigned short*)alloc((size_t)Ntok * 1536 * 2);
  unsigned short* qr16  = (unsigned short*)alloc((size_t)24 * 1024 * 128 * 2);
  unsigned short* kr16  = (unsigned short*)alloc((size_t)24 * 1024 * 128 * 2);
  unsigned short* vr16  = (unsigned short*)alloc((size_t)24 * 64 * 2048 * 2);
  unsigned short* xb16  = (unsigned short*)alloc((size_t)Ec * CAPPc * 1536 * 2);
  unsigned short* wo16  = (unsigned short*)alloc((size_t)768 * 1536 * 2);
  unsigned short* xf16  = (unsigned short*)alloc((size_t)Ntok * 768 * 2);
  char* spb = alloc((size_t)24 * 1024 * 1024 * 4);           // scratch region
  float* yexp = (float*)spb;                                 // [0, 9.4M)
  unsigned short* act16 = (unsigned short*)(spb + 50331648); // [50.3M, 75.5M)
  unsigned short* wq16  = (unsigned short*)(spb + 75497472); // [75.5M, 82.6M)
  unsigned short* w13_16 = (unsigned short*)alloc((size_t)Ec * 4096 * 1536 * 2); // 100.66MB
  unsigned short* wt16   = w13_16;                           // alias (used after)
  unsigned short* w2_16  = (unsigned short*)alloc((size_t)Ec * 768 * 4096 * 2);  // 50.3MB
  int* top    = (int*)alloc(Ntok * 4);
  int* rankb  = (int*)alloc(Ntok * 4);
  int* cnt    = (int*)alloc(Lc * Ec * 4);
  float* psum = (float*)alloc(Lc * Ec * 4);
  float* z2   = (float*)alloc(Lc * 4);

  zero_small<<<1, 64, 0, stream>>>(psum, z2);
  embed_k<<<Ntok, 192, 0, stream>>>(idx, wte, x, x16);

  for (int l = 0; l < Lc; ++l) {
    split2_wT<1, 0><<<dim3(72, 24, 1), 256, 0, stream>>>(wqkv + (size_t)l * 768 * 2304,
                                                         wq16, 768, 2304, 0, 0);
    split2_wT<1, 0><<<dim3(24, 24, 1), 256, 0, stream>>>(oproj + (size_t)l * 768 * 768,
                                                         wo16, 768, 768, 0, 0);
    if (l == 0) {
      split2_wT<1, 1><<<dim3(128, 24, 8), 256, 0, stream>>>(w13, w13_16,
          768, 4096, (long long)768 * 4096, (long long)4096 * 1536);
      split2_wT<1, 0><<<dim3(24, 64, 8), 256, 0, stream>>>(w2p, w2_16,
          2048, 768, (long long)2048 * 768, (long long)768 * 4096);
    } else {
      split2_wT<0, 1><<<dim3(128, 24, 8), 256, 0, stream>>>(w13 + (size_t)Ec * 768 * 4096,
          w13_16, 768, 4096, (long long)768 * 4096, (long long)4096 * 768);
      split2_wT<0, 0><<<dim3(24, 64, 8), 256, 0, stream>>>(w2p + (size_t)Ec * 2048 * 768,
          w2_16, 2048, 768, (long long)2048 * 768, (long long)768 * 2048);
    }
    // qkv = x @ wqkv[l]
    gemm_h<128, 1, 0, 0, 0><<<288, 256, 0, stream>>>(
        x16, wq16, qkv, nullptr, 2048, 2304, 768, 2304, 16, 18, 0, 0, 1, 0, 0);
    // fused q/k rmsnorm + rope + V transpose
    qk_rope<<<Ntok, 256, 0, stream>>>(qkv, qnw + l * 768, knw + l * 768, qr16, kr16, vr16);
    // fused attention -> yfl16 (split-fp16)
    flash_attn<<<384, 256, 0, stream>>>(qr16, kr16, vr16, yfl16);
    // h = x + y @ o_proj[l]
    gemm_h<64, 1, 1, 0, 0><<<192, 256, 0, stream>>>(
        yfl16, wo16, hbuf, x, 2048, 768, 768, 768, 16, 12, 0, 0, 1, 0, 0);
    rmsnorm_k<<<Ntok, 256, 0, stream>>>(hbuf, 768, ffn, 768, ffnw + l * 768);
    gate_k<<<Ntok / 256, 256, 0, stream>>>(ffn, gatew + (size_t)l * 768 * 8, top,
                                           psum + l * 8, z2 + l);
    route_scan<<<1, 64, 0, stream>>>(top, rankb, cnt + l * 8);
    if (l == 0) {
      scatter_xb<1><<<Ntok, 192, 0, stream>>>(ffn, top, rankb, xb16);
      // act16 = silu(g)*u fused epilogue (g/u-interleaved w13_16)
      gemm_h<128, 1, 0, 0, 1><<<768, 256, 0, stream>>>(
          xb16, w13_16, (float*)act16, nullptr, 384, 4096, 768, 4096, 3, 32,
          (long long)384 * 1536, (long long)4096 * 1536, 1, (long long)384 * 4096, 0);
      gemm_h<64, 1, 0, 0, 0><<<288, 256, 0, stream>>>(
          act16, w2_16, yexp, nullptr, 384, 768, 2048, 768, 3, 12,
          (long long)384 * 4096, (long long)768 * 4096, 1, (long long)384 * 768, 0);
    } else {
      scatter_xb<0><<<Ntok, 192, 0, stream>>>(ffn, top, rankb, xb16);
      gemm_h<128, 0, 0, 0, 2><<<768, 256, 0, stream>>>(
          xb16, w13_16, (float*)act16, nullptr, 384, 4096, 768, 2048, 3, 32,
          (long long)384 * 768, (long long)4096 * 768, 1, (long long)384 * 2048, 0);
      gemm_h<64, 0, 0, 0, 0><<<288, 256, 0, stream>>>(
          act16, w2_16, yexp, nullptr, 384, 768, 2048, 768, 3, 12,
          (long long)384 * 2048, (long long)768 * 2048, 1, (long long)384 * 768, 0);
    }
    gather_add<<<Ntok, 192, 0, stream>>>(hbuf, yexp, top, rankb, x, x16);
  }

  rmsnorm_h<<<Ntok, 256, 0, stream>>>(x, xf16, lnf);
  f2h4<<<(int)(((long long)Vc * 768 / 4 + 255) / 256), 256, 0, stream>>>(
      wte, wt16, (long long)Vc * 768 / 4);
  // logits = xf @ wte^T : 256x128 tile, BK=32, 3-buffer dist-2, 2 blocks/CU
  gemm_logits<<<8 * 393, 512, 0, stream>>>(xf16, wt16, out, 2048, Vc, 768, Vc, 8);
  aux_fin<<<1, 64, 0, stream>>>(psum, cnt, z2, out + LOGITS_N);
}

// Round 11
// 1244.104 us; speedup vs baseline: 1.1332x; 1.1332x over previous
//
// LunarisCodex MoE-GPT forward, MI355X/gfx950. Round 11: revert logits to the
// R9 kernel (BK=64, 3x48KB dist-2 single-barrier, plain stores — R10's nt-store
// write amplification 419->778MB and BK=32 MFMA-starvation both reverted).
// zero_small folded into embed_k.
#include <hip/hip_runtime.h>

typedef __attribute__((ext_vector_type(8))) _Float16 half8;
typedef __attribute__((ext_vector_type(4))) float f32x4;

constexpr int Bc = 2, Tc = 1024, Dc = 768, NHc = 12, HDc = 64;
constexpr int Vc = 50257, Lc = 2, Ec = 8, Hc = 2048;
constexpr int Ntok = Bc * Tc;            // 2048
constexpr int CAPc = 320, CAPPc = 384;   // capacity, padded rows per expert
constexpr long long LOGITS_N = (long long)Bc * Tc * Vc;  // 102926336

typedef const __attribute__((address_space(1))) unsigned int* gas_t;
typedef __attribute__((address_space(3))) unsigned int* las_t;
__device__ __forceinline__ void gload16(const void* g, void* l) {
  __builtin_amdgcn_global_load_lds((gas_t)g, (las_t)l, 16, 0, 0);
}

__device__ __forceinline__ void splitf16(float a, unsigned short& h, unsigned short& l) {
  _Float16 hh = (_Float16)a;                       // RNE
  _Float16 ll = (_Float16)(a - (float)hh);
  h = __builtin_bit_cast(unsigned short, hh);
  l = __builtin_bit_cast(unsigned short, ll);
}
__device__ __forceinline__ unsigned short f16o(float a) {
  _Float16 hh = (_Float16)a;
  return __builtin_bit_cast(unsigned short, hh);
}

// ---------------- small kernels ----------------

// embed: x (f32) + x16 (split-fp16 [hi768|lo768]); block 0 also zeroes psum/z2
__global__ void embed_k(const int* __restrict__ idx, const float* __restrict__ wte,
                        float* __restrict__ x, unsigned short* __restrict__ x16,
                        float* __restrict__ psum, float* __restrict__ z2) {
  int n = blockIdx.x;
  int t = threadIdx.x;
  if (n == 0) {
    if (t < Lc * Ec) psum[t] = 0.f;
    if (t >= 32 && t < 32 + Lc) z2[t - 32] = 0.f;
  }
  long long v = idx[n];
  const float4* src = (const float4*)(wte + v * 768);
  float4* dst = (float4*)(x + (long long)n * 768);
  if (t < 192) {
    float4 val = src[t];
    dst[t] = val;
    ushort4 h, l;
    splitf16(val.x, h.x, l.x); splitf16(val.y, h.y, l.y);
    splitf16(val.z, h.z, l.z); splitf16(val.w, h.w, l.w);
    unsigned short* d = x16 + (long long)n * 1536 + t * 4;
    *(ushort4*)d = h;
    *(ushort4*)(d + 768) = l;
  }
}

// f32 -> fp16 single (for wte)
__global__ void f2h4(const float* __restrict__ in, unsigned short* __restrict__ out,
                     long long n4) {
  long long i = (long long)blockIdx.x * 256 + threadIdx.x;
  if (i >= n4) return;
  float4 v = ((const float4*)in)[i];
  ushort4 o;
  o.x = f16o(v.x); o.y = f16o(v.y); o.z = f16o(v.z); o.w = f16o(v.w);
  ((ushort4*)out)[i] = o;
}

// f32 weights (K,N) -> fp16 transposed. SP=1: (N,2K) [hi|lo]; SP=0: (N,K).
// ILV=1: dst row remapped for g/u interleave: n' = (h>>4)*32 + is_u*16 + (h&15),
// h = n&2047, is_u = n>>11 (requires N=4096).
template <int SP, int ILV>
__global__ void __launch_bounds__(256) split2_wT(const float* __restrict__ src,
    unsigned short* __restrict__ dst, int K, int N, long long sS, long long sD) {
  __shared__ float t[32][33];
  int z = blockIdx.z;
  src += (long long)z * sS;
  dst += (long long)z * sD;
  int n0 = blockIdx.x * 32, k0 = blockIdx.y * 32;
  int tid = threadIdx.x;
  int r = tid >> 3, c4 = (tid & 7) * 4;
  float4 v = *(const float4*)(src + (long long)(k0 + r) * N + n0 + c4);
  t[r][c4 + 0] = v.x; t[r][c4 + 1] = v.y; t[r][c4 + 2] = v.z; t[r][c4 + 3] = v.w;
  __syncthreads();
  int n = tid >> 3, kq = (tid & 7) * 4;
  ushort4 h, l;
  splitf16(t[kq + 0][n], h.x, l.x);
  splitf16(t[kq + 1][n], h.y, l.y);
  splitf16(t[kq + 2][n], h.z, l.z);
  splitf16(t[kq + 3][n], h.w, l.w);
  const int lda = SP ? 2 * K : K;
  int nd = n0 + n;
  if (ILV) {
    int hh = nd & 2047, iu = nd >> 11;
    nd = ((hh >> 4) << 5) + (iu << 4) + (hh & 15);
  }
  unsigned short* d = dst + (long long)nd * lda + k0 + kq;
  *(ushort4*)d = h;
  if (SP) *(ushort4*)(d + K) = l;
}

// rmsnorm over 768 cols; strided in/out, f32 out
__global__ void __launch_bounds__(256) rmsnorm_k(const float* in, int istride,
                                                 float* outp, int ostride,
                                                 const float* w) {
  long long n = blockIdx.x;
  const float* xr = in + n * istride;
  float* yr = outp + n * ostride;
  int tid = threadIdx.x;
  float s = 0.f;
  for (int i = tid; i < 768; i += 256) { float v = xr[i]; s += v * v; }
  #pragma unroll
  for (int o = 32; o; o >>= 1) s += __shfl_down(s, o);
  __shared__ float red[4];
  __shared__ float bs;
  if ((tid & 63) == 0) red[tid >> 6] = s;
  __syncthreads();
  if (tid == 0) bs = rsqrtf((red[0] + red[1] + red[2] + red[3]) / 768.0f + 1e-5f);
  __syncthreads();
  float sc = bs;
  for (int i = tid; i < 768; i += 256) yr[i] = xr[i] * sc * w[i];
}

// rmsnorm -> fp16 single output (final ln before logits)
__global__ void __launch_bounds__(256) rmsnorm_h(const float* in,
                                                 unsigned short* outp, const float* w) {
  long long n = blockIdx.x;
  const float* xr = in + n * 768;
  unsigned short* yr = outp + n * 768;
  int tid = threadIdx.x;
  float s = 0.f;
  for (int i = tid; i < 768; i += 256) { float v = xr[i]; s += v * v; }
  #pragma unroll
  for (int o = 32; o; o >>= 1) s += __shfl_down(s, o);
  __shared__ float red[4];
  __shared__ float bs;
  if ((tid & 63) == 0) red[tid >> 6] = s;
  __syncthreads();
  if (tid == 0) bs = rsqrtf((red[0] + red[1] + red[2] + red[3]) / 768.0f + 1e-5f);
  __syncthreads();
  float sc = bs;
  for (int i = tid; i < 768; i += 256) yr[i] = f16o(xr[i] * sc * w[i]);
}

// fused q/k rmsnorm + RoPE + V transpose. One block per token.
__global__ void __launch_bounds__(256) qk_rope(const float* __restrict__ qkv,
    const float* __restrict__ qnw, const float* __restrict__ knw,
    unsigned short* __restrict__ qr, unsigned short* __restrict__ kr,
    unsigned short* __restrict__ vr) {
  int n = blockIdx.x;
  int t = n & 1023, b = n >> 10;
  const float* row = qkv + (long long)n * 2304;
  int tid = threadIdx.x;
  float sq = 0.f, sk = 0.f;
  for (int i = tid; i < 768; i += 256) {
    float q = row[i]; sq += q * q;
    float k = row[768 + i]; sk += k * k;
  }
  #pragma unroll
  for (int o = 32; o; o >>= 1) { sq += __shfl_down(sq, o); sk += __shfl_down(sk, o); }
  __shared__ float redq[4], redk[4];
  __shared__ float bq, bk;
  if ((tid & 63) == 0) { redq[tid >> 6] = sq; redk[tid >> 6] = sk; }
  __syncthreads();
  if (tid == 0) {
    bq = rsqrtf((redq[0] + redq[1] + redq[2] + redq[3]) / 768.0f + 1e-5f);
    bk = rsqrtf((redk[0] + redk[1] + redk[2] + redk[3]) / 768.0f + 1e-5f);
  }
  __syncthreads();
  float nq = bq, nk = bk;
  for (int i = tid; i < 384; i += 256) {
    int hh = i >> 5, j = i & 31;
    int c = hh * 64 + 2 * j;
    float ang = (float)t * powf(10000.0f, -((float)j * (1.0f / 32.0f)));
    float cs = cosf(ang), sn = sinf(ang);
    int z = b * 12 + hh;
    long long qb = ((long long)z * 1024 + t) * 128 + 2 * j;
    unsigned short h0, l0, h1, l1;
    float q0 = row[c] * nq * qnw[c], q1 = row[c + 1] * nq * qnw[c + 1];
    splitf16(q0 * cs - q1 * sn, h0, l0);
    splitf16(q0 * sn + q1 * cs, h1, l1);
    *(unsigned int*)&qr[qb] = (unsigned)h0 | ((unsigned)h1 << 16);
    *(unsigned int*)&qr[qb + 64] = (unsigned)l0 | ((unsigned)l1 << 16);
    float k0 = row[768 + c] * nk * knw[c], k1 = row[768 + c + 1] * nk * knw[c + 1];
    splitf16(k0 * cs - k1 * sn, h0, l0);
    splitf16(k0 * sn + k1 * cs, h1, l1);
    *(unsigned int*)&kr[qb] = (unsigned)h0 | ((unsigned)h1 << 16);
    *(unsigned int*)&kr[qb + 64] = (unsigned)l0 | ((unsigned)l1 << 16);
    splitf16(row[1536 + c], h0, l0);
    splitf16(row[1536 + c + 1], h1, l1);
    long long vb = ((long long)z * 64 + 2 * j) * 2048 + t;
    vr[vb] = h0; vr[vb + 1024] = l0;
    vr[vb + 2048] = h1; vr[vb + 3072] = l1;
  }
}

// ---------------- fused flash attention ----------------
__global__ void __launch_bounds__(256) flash_attn(
    const unsigned short* __restrict__ qr, const unsigned short* __restrict__ kr,
    const unsigned short* __restrict__ vr, unsigned short* __restrict__ yout) {
  __shared__ __align__(16) unsigned short Ph[4][16][72];
  __shared__ __align__(16) unsigned short Pl[4][16][72];
  int bid = blockIdx.x;
  int z = bid >> 4;
  int qt = 15 - (bid & 15);          // heavy tiles first (load balance)
  int b = z / 12, h = z % 12;
  int q0 = qt * 64;
  int wave = threadIdx.x >> 6, lane = threadIdx.x & 63;
  int lr = lane & 15, lg = lane >> 4;
  int qw = q0 + wave * 16;           // this wave's 16 q rows
  half8 af[2][2];
  const unsigned short* qbase = qr + ((long long)z * 1024 + qw + lr) * 128;
  #pragma unroll
  for (int ks = 0; ks < 2; ++ks)
    #pragma unroll
    for (int p = 0; p < 2; ++p)
      af[ks][p] = *(const half8*)(qbase + p * 64 + ks * 32 + lg * 8);
  f32x4 accy[4];
  #pragma unroll
  for (int df = 0; df < 4; ++df) accy[df] = (f32x4){0.f, 0.f, 0.f, 0.f};
  float mrun[4] = {-3.4e38f, -3.4e38f, -3.4e38f, -3.4e38f};
  float srun[4] = {0.f, 0.f, 0.f, 0.f};
  for (int kt = 0; kt <= qt; ++kt) {
    int kv0 = kt * 64;
    f32x4 s[4];
    #pragma unroll
    for (int nf = 0; nf < 4; ++nf) s[nf] = (f32x4){0.f, 0.f, 0.f, 0.f};
    const unsigned short* kbase = kr + ((long long)z * 1024 + kv0 + lr) * 128;
    #pragma unroll
    for (int nf = 0; nf < 4; ++nf) {
      const unsigned short* kb = kbase + nf * 16 * 128;
      #pragma unroll
      for (int ks = 0; ks < 2; ++ks) {
        half8 bh = *(const half8*)(kb + ks * 32 + lg * 8);
        half8 bl = *(const half8*)(kb + 64 + ks * 32 + lg * 8);
        s[nf] = __builtin_amdgcn_mfma_f32_16x16x32_f16(af[ks][0], bh, s[nf], 0, 0, 0);
        s[nf] = __builtin_amdgcn_mfma_f32_16x16x32_f16(af[ks][1], bh, s[nf], 0, 0, 0);
        s[nf] = __builtin_amdgcn_mfma_f32_16x16x32_f16(af[ks][0], bl, s[nf], 0, 0, 0);
      }
    }
    bool diag = (kt == qt);
    #pragma unroll
    for (int nf = 0; nf < 4; ++nf)
      #pragma unroll
      for (int j = 0; j < 4; ++j) {
        float v = s[nf][j] * 0.125f;
        if (diag && (nf * 16 + lr > wave * 16 + lg * 4 + j)) v = -1e30f;
        s[nf][j] = v;
      }
    #pragma unroll
    for (int j = 0; j < 4; ++j) {
      float tm = fmaxf(fmaxf(s[0][j], s[1][j]), fmaxf(s[2][j], s[3][j]));
      #pragma unroll
      for (int o = 1; o < 16; o <<= 1) tm = fmaxf(tm, __shfl_xor(tm, o));
      float mnew = fmaxf(mrun[j], tm);
      float sc = expf(mrun[j] - mnew);
      float ts = 0.f;
      #pragma unroll
      for (int nf = 0; nf < 4; ++nf) {
        float p = expf(s[nf][j] - mnew);
        ts += p;
        unsigned short ph, pl;
        splitf16(p, ph, pl);
        Ph[wave][lg * 4 + j][nf * 16 + lr] = ph;
        Pl[wave][lg * 4 + j][nf * 16 + lr] = pl;
      }
      #pragma unroll
      for (int o = 1; o < 16; o <<= 1) ts += __shfl_xor(ts, o);
      srun[j] = srun[j] * sc + ts;
      mrun[j] = mnew;
      #pragma unroll
      for (int df = 0; df < 4; ++df) accy[df][j] *= sc;
    }
    #pragma unroll
    for (int ks2 = 0; ks2 < 2; ++ks2) {
      half8 aph = *(const half8*)&Ph[wave][lr][ks2 * 32 + lg * 8];
      half8 apl = *(const half8*)&Pl[wave][lr][ks2 * 32 + lg * 8];
      #pragma unroll
      for (int df = 0; df < 4; ++df) {
        const unsigned short* vb =
            vr + ((long long)z * 64 + df * 16 + lr) * 2048 + kv0 + ks2 * 32 + lg * 8;
        half8 bvh = *(const half8*)vb;
        half8 bvl = *(const half8*)(vb + 1024);
        accy[df] = __builtin_amdgcn_mfma_f32_16x16x32_f16(aph, bvh, accy[df], 0, 0, 0);
        accy[df] = __builtin_amdgcn_mfma_f32_16x16x32_f16(apl, bvh, accy[df], 0, 0, 0);
        accy[df] = __builtin_amdgcn_mfma_f32_16x16x32_f16(aph, bvl, accy[df], 0, 0, 0);
      }
    }
  }
  float inv[4];
  #pragma unroll
  for (int j = 0; j < 4; ++j) inv[j] = 1.0f / srun[j];
  #pragma unroll
  for (int df = 0; df < 4; ++df)
    #pragma unroll
    for (int j = 0; j < 4; ++j) {
      long long tok = (long long)b * 1024 + qw + lg * 4 + j;
      int col = h * 64 + df * 16 + lr;
      unsigned short hh, ll;
      splitf16(accy[df][j] * inv[j], hh, ll);
      yout[tok * 1536 + col] = hh;
      yout[tok * 1536 + 768 + col] = ll;
    }
}

// gate: logits(f32), softmax probs, argmax (first-max), aux accumulators
__global__ void __launch_bounds__(256) gate_k(const float* __restrict__ xin,
    const float* __restrict__ gw, int* __restrict__ top,
    float* __restrict__ psum, float* __restrict__ z2) {
  __shared__ float gws[768 * 8];
  __shared__ float pacc[8];
  __shared__ float zacc;
  int tid = threadIdx.x;
  for (int i = tid; i < 768 * 8 / 4; i += 256) ((float4*)gws)[i] = ((const float4*)gw)[i];
  if (tid < 8) pacc[tid] = 0.f;
  if (tid == 0) zacc = 0.f;
  __syncthreads();
  int n = blockIdx.x * 256 + tid;
  const float4* xr4 = (const float4*)(xin + (long long)n * 768);
  float l[8] = {0, 0, 0, 0, 0, 0, 0, 0};
  for (int d4 = 0; d4 < 192; ++d4) {
    float4 xv = xr4[d4];
    const float* g = &gws[d4 * 32];
    #pragma unroll
    for (int e = 0; e < 8; ++e)
      l[e] += xv.x * g[e] + xv.y * g[8 + e] + xv.z * g[16 + e] + xv.w * g[24 + e];
  }
  float mx = l[0]; int bi = 0;
  #pragma unroll
  for (int e = 1; e < 8; ++e) if (l[e] > mx) { mx = l[e]; bi = e; }  // first-max
  float p[8]; float se = 0.f;
  #pragma unroll
  for (int e = 0; e < 8; ++e) { p[e] = expf(l[e] - mx); se += p[e]; }
  float z = mx + logf(se);
  top[n] = bi;
  #pragma unroll
  for (int e = 0; e < 8; ++e) atomicAdd(&pacc[e], p[e] / se);
  atomicAdd(&zacc, z * z);
  __syncthreads();
  if (tid < 8) atomicAdd(&psum[tid], pacc[tid]);
  if (tid == 0) atomicAdd(z2, zacc);
}

// single-wave rank scan (matches stable argsort arrival order)
__global__ void route_scan(const int* __restrict__ top, int* __restrict__ rank,
                           int* __restrict__ cnt) {
  int lane = threadIdx.x;
  int c[8] = {0, 0, 0, 0, 0, 0, 0, 0};
  unsigned long long below = (1ull << lane) - 1ull;
  for (int s = 0; s < Ntok / 64; ++s) {
    int n = s * 64 + lane;
    int e = top[n];
    int r = 0;
    #pragma unroll
    for (int q = 0; q < 8; ++q) {
      unsigned long long m = __ballot(e == q);
      if (e == q) r = c[q] + __popcll(m & below);
      c[q] += __popcll(m);
    }
    rank[n] = r;
  }
  #pragma unroll
  for (int q = 0; q < 8; ++q) if (lane == q) cnt[q] = c[q];
}

// ffn f32 -> xb16. SP=1: (row,1536=[hi|lo]); SP=0: (row,768) hi only.
template <int SP>
__global__ void scatter_xb(const float* __restrict__ xin, const int* __restrict__ top,
                           const int* __restrict__ rank, unsigned short* __restrict__ xb) {
  int n = blockIdx.x;
  int r = rank[n];
  if (r >= CAPc) return;
  int e = top[n];
  int t = threadIdx.x;
  if (t >= 192) return;
  float4 v = ((const float4*)(xin + (long long)n * 768))[t];
  ushort4 h, l;
  splitf16(v.x, h.x, l.x); splitf16(v.y, h.y, l.y);
  splitf16(v.z, h.z, l.z); splitf16(v.w, h.w, l.w);
  const int lda = SP ? 1536 : 768;
  unsigned short* dst = xb + ((long long)e * CAPPc + r) * lda + t * 4;
  *(ushort4*)dst = h;
  if (SP) *(ushort4*)(dst + 768) = l;
}

// h + expert-out -> x (f32) AND x16 (split-fp16) for next layer
__global__ void gather_add(const float* __restrict__ h, const float* __restrict__ yexp,
                           const int* __restrict__ top, const int* __restrict__ rank,
                           float* __restrict__ xo, unsigned short* __restrict__ x16) {
  int n = blockIdx.x;
  int r = rank[n], e = top[n];
  bool kept = r < CAPc;
  int rc = kept ? r : (CAPc - 1);
  const float4* hs = (const float4*)(h + (long long)n * 768);
  const float4* ys = (const float4*)(yexp + ((long long)e * CAPPc + rc) * 768);
  float4* dst = (float4*)(xo + (long long)n * 768);
  int t = threadIdx.x;
  if (t < 192) {
    float4 v = hs[t];
    if (kept) { float4 y = ys[t]; v.x += y.x; v.y += y.y; v.z += y.z; v.w += y.w; }
    dst[t] = v;
    ushort4 hh, ll;
    splitf16(v.x, hh.x, ll.x); splitf16(v.y, hh.y, ll.y);
    splitf16(v.z, hh.z, ll.z); splitf16(v.w, hh.w, ll.w);
    unsigned short* d = x16 + (long long)n * 1536 + t * 4;
    *(ushort4*)d = hh;
    *(ushort4*)(d + 768) = ll;
  }
}

__global__ void aux_fin(const float* __restrict__ psum, const int* __restrict__ cnt,
                        const float* __restrict__ z2, float* __restrict__ outp) {
  if (threadIdx.x == 0) {
    float aux = 0.f;
    for (int l = 0; l < Lc; ++l) {
      float bl = 0.f;
      for (int e = 0; e < 8; ++e)
        bl += (psum[l * 8 + e] * (1.0f / 2048.0f)) * ((float)cnt[l * 8 + e] * (1.0f / 2048.0f));
      aux += bl * (0.01f * 8.0f) + (z2[l] * (1.0f / 2048.0f)) * 0.001f;
    }
    outp[0] = aux;
  }
}

// ---------------- fp16 MFMA GEMM (single-barrier pipelined dbuf) ----------
// C(M,N) f32 [+Add] = A @ Bt^T. SPLIT=1: [hi K|lo K] (lda=2K), 3 MFMA terms per
// 32-k-slice (4 planes). SPLIT=0: lda=K, BK=64 (2 planes).
// SILU: 1 = silu(g)*u -> split-fp16 act (g/u-interleaved B, BN=128); 2 = single.
template <int BN, int SPLIT, int ADD, int NTAIL, int SILU>
__global__ void __launch_bounds__(256) gemm_h(
    const unsigned short* __restrict__ A, const unsigned short* __restrict__ Bt,
    float* __restrict__ C, const float* __restrict__ Add,
    int M, int N, int K, int ldc, int gx, int gy,
    long long sA, long long sB, int zdiv, long long sC1, long long sC2) {
  constexpr int FN = (BN == 128) ? 4 : 2;
  constexpr int APL = 128 * 32;            // A plane (shorts)
  constexpr int BPL = BN * 32;             // B plane (shorts)
  constexpr int BUF = 2 * APL + 2 * BPL;   // Ah|Al|Bh|Bl
  __shared__ __align__(16) unsigned short lds[2][BUF];
  int tot = gridDim.x;
  int lin = blockIdx.x;
  if ((tot & 7) == 0) lin = (lin & 7) * (tot >> 3) + (lin >> 3);  // XCD chunking
  int pz = lin / (gx * gy);
  int r2 = lin - pz * (gx * gy);
  const int m0 = (r2 % gx) * 128, n0 = (r2 / gx) * BN;
  A += (long long)pz * sA;
  Bt += (long long)pz * sB;
  const long long co = (long long)(pz / zdiv) * sC1 + (long long)(pz % zdiv) * sC2;
  const int lda = SPLIT ? 2 * K : K;
  const int NS = SPLIT ? K / 32 : K / 64;
  const int tid = threadIdx.x;
  const int lane = tid & 63, wave = tid >> 6;
  const int wm = (BN == 128) ? (wave >> 1) : (wave & 1);
  const int wn = (BN == 128) ? (wave & 1) : (wave >> 1);
  const int srow = tid >> 2, scol = (tid & 3) * 8;
  const unsigned short* Ar = A + (long long)(m0 + srow) * lda + scol;
  int br0 = n0 + srow;
  if (NTAIL) br0 = min(br0, N - 1);
  const unsigned short* Br = Bt + (long long)br0 * lda + scol;
  int br1 = n0 + srow + 64;
  if (NTAIL) br1 = min(br1, N - 1);
  const unsigned short* Br2 = Bt + (long long)br1 * lda + scol;

  auto STAGE = [&](int buf, int s) {
    const int kh = SPLIT ? s * 32 : s * 64;
    const int kl = SPLIT ? K + s * 32 : s * 64 + 32;
    unsigned short* L = lds[buf];
    gload16(Ar + kh, &L[wave * 512]);
    gload16(Ar + (long long)64 * lda + kh, &L[2048 + wave * 512]);
    gload16(Ar + kl, &L[APL + wave * 512]);
    gload16(Ar + (long long)64 * lda + kl, &L[APL + 2048 + wave * 512]);
    gload16(Br + kh, &L[2 * APL + wave * 512]);
    gload16(Br + kl, &L[2 * APL + BPL + wave * 512]);
    if (BN == 128) {
      gload16(Br2 + kh, &L[2 * APL + 2048 + wave * 512]);
      gload16(Br2 + kl, &L[2 * APL + BPL + 2048 + wave * 512]);
    }
  };

  f32x4 acc[4][FN];
  #pragma unroll
  for (int m = 0; m < 4; ++m)
    #pragma unroll
    for (int n = 0; n < FN; ++n) acc[m][n] = (f32x4){0.f, 0.f, 0.f, 0.f};

  STAGE(0, 0);
  int cur = 0;
  for (int s = 0; s < NS; ++s) {
    asm volatile("s_waitcnt vmcnt(0)" ::: "memory");   // own stage-s loads landed
    __builtin_amdgcn_sched_barrier(0);
    __builtin_amdgcn_s_barrier();   // all waves: stage-s in LDS; prev reads retired
    if (s + 1 < NS) STAGE(cur ^ 1, s + 1);   // overlaps with reads+MFMA below
    const unsigned short* L = lds[cur];
    half8 bfh[FN], bfl[FN];
    #pragma unroll
    for (int n = 0; n < FN; ++n) {
      int bo = (wn * (FN * 16) + n * 16 + (lane & 15)) * 32 + (lane >> 4) * 8;
      bfh[n] = *(const half8*)&L[2 * APL + bo];
      bfl[n] = *(const half8*)&L[2 * APL + BPL + bo];
    }
    __builtin_amdgcn_s_setprio(1);
    #pragma unroll
    for (int m = 0; m < 4; ++m) {
      int ao = (wm * 64 + m * 16 + (lane & 15)) * 32 + (lane >> 4) * 8;
      half8 afh = *(const half8*)&L[ao];
      half8 afl = *(const half8*)&L[APL + ao];
      #pragma unroll
      for (int n = 0; n < FN; ++n) {
        acc[m][n] = __builtin_amdgcn_mfma_f32_16x16x32_f16(afh, bfh[n], acc[m][n], 0, 0, 0);
        if (SPLIT) {
          acc[m][n] = __builtin_amdgcn_mfma_f32_16x16x32_f16(afl, bfh[n], acc[m][n], 0, 0, 0);
          acc[m][n] = __builtin_amdgcn_mfma_f32_16x16x32_f16(afh, bfl[n], acc[m][n], 0, 0, 0);
        } else {
          acc[m][n] = __builtin_amdgcn_mfma_f32_16x16x32_f16(afl, bfl[n], acc[m][n], 0, 0, 0);
        }
      }
    }
    __builtin_amdgcn_s_setprio(0);
    cur ^= 1;
  }
  if constexpr (SILU) {
    // g/u-interleaved cols: nf even = g, nf odd = u for the same 16-h block.
    unsigned short* act = (unsigned short*)C;
    #pragma unroll
    for (int m = 0; m < 4; ++m)
      #pragma unroll
      for (int p = 0; p < FN / 2; ++p) {
        f32x4 g = acc[m][2 * p], u = acc[m][2 * p + 1];
        int colh = ((n0 + wn * (FN * 16)) >> 1) + p * 16 + (lane & 15);
        #pragma unroll
        for (int j = 0; j < 4; ++j) {
          long long row = m0 + wm * 64 + m * 16 + (lane >> 4) * 4 + j;
          float gv = g[j];
          float a = gv / (1.f + expf(-gv)) * u[j];
          long long o = co + row * ldc + colh;
          if (SILU == 1) {
            unsigned short hh, ll;
            splitf16(a, hh, ll);
            act[o] = hh;
            act[o + 2048] = ll;
          } else {
            act[o] = f16o(a);
          }
        }
      }
  } else {
    #pragma unroll
    for (int m = 0; m < 4; ++m)
      #pragma unroll
      for (int n = 0; n < FN; ++n) {
        int col = n0 + wn * (FN * 16) + n * 16 + (lane & 15);
        if (!NTAIL || col < N) {
          #pragma unroll
          for (int j = 0; j < 4; ++j) {
            long long row = m0 + wm * 64 + m * 16 + (lane >> 4) * 4 + j;
            long long o = co + row * ldc + col;
            float v = acc[m][n][j];
            if (ADD) v += Add[o];
            C[o] = v;
          }
        }
      }
  }
}

// ---------------- logits GEMM: 256x128 tile, 3-buffer distance-2 pipeline ----
// (R9 version — best measured.) Per step: vmcnt(6) -> ONE s_barrier -> STAGE(s+2
// -> buf[(s+2)%3]) -> ds_read buf[s%3] -> MFMA. Plain f32 stores (no nt).
__global__ void __launch_bounds__(512) gemm_logits(
    const unsigned short* __restrict__ A, const unsigned short* __restrict__ Bt,
    float* __restrict__ C, int M, int N, int K, int ldc, int gx) {
  constexpr int BUFS = 24576;            // shorts per buffer (48KB)
  constexpr int BOFF = 16384;            // B region offset (shorts)
  __shared__ __align__(16) unsigned short lds[3 * BUFS];   // 144KB
  int tot = gridDim.x;
  int lin = blockIdx.x;
  if ((tot & 7) == 0) lin = (lin & 7) * (tot >> 3) + (lin >> 3);  // XCD chunking
  const int m0 = (lin % gx) * 256, n0 = (lin / gx) * 128;
  const int tid = threadIdx.x;
  const int lane = tid & 63;
  const int wm = (tid >> 6) >> 1, wn = (tid >> 6) & 1;
  const int NS = K / 64;   // 12

  auto STAGE = [&](int buf, int t) {
    const int k0 = t * 64;
    unsigned short* L = lds + buf * BUFS;
    #pragma unroll
    for (int i = 0; i < 4; ++i) {                     // A: 256x64
      int idx = tid + i * 512;
      int row = idx >> 3, blk = idx & 7;
      gload16(A + (long long)(m0 + row) * K + k0 + ((blk ^ (row & 7)) << 3),
              L + idx * 8);
    }
    #pragma unroll
    for (int i = 0; i < 2; ++i) {                     // B: 128x64
      int idx = tid + i * 512;
      int row = idx >> 3, blk = idx & 7;
      int br = min(n0 + row, N - 1);
      gload16(Bt + (long long)br * K + k0 + ((blk ^ (row & 7)) << 3),
              L + BOFF + idx * 8);
    }
  };

  f32x4 acc[4][4];
  #pragma unroll
  for (int mf = 0; mf < 4; ++mf)
    #pragma unroll
    for (int nf = 0; nf < 4; ++nf) acc[mf][nf] = (f32x4){0.f, 0.f, 0.f, 0.f};

  STAGE(0, 0); STAGE(1, 1);
  for (int s = 0; s < NS; ++s) {
    if (s + 1 < NS) asm volatile("s_waitcnt vmcnt(6)" ::: "memory");
    else            asm volatile("s_waitcnt vmcnt(0)" ::: "memory");
    __builtin_amdgcn_sched_barrier(0);
    __builtin_amdgcn_s_barrier();          // tile s ready; buf[(s+2)%3] released
    if (s + 2 < NS) STAGE((s + 2) % 3, s + 2);   // overlaps with reads+MFMA
    const unsigned short* L = lds + (s % 3) * BUFS;
    half8 a[4][2], b[4][2];
    #pragma unroll
    for (int mf = 0; mf < 4; ++mf)
      #pragma unroll
      for (int ks = 0; ks < 2; ++ks) {
        int row = wm * 64 + mf * 16 + (lane & 15);
        int blk = (ks * 4 + (lane >> 4)) ^ (row & 7);
        a[mf][ks] = *(const half8*)(L + row * 64 + blk * 8);
      }
    #pragma unroll
    for (int nf = 0; nf < 4; ++nf)
      #pragma unroll
      for (int ks = 0; ks < 2; ++ks) {
        int row = wn * 64 + nf * 16 + (lane & 15);
        int blk = (ks * 4 + (lane >> 4)) ^ (row & 7);
        b[nf][ks] = *(const half8*)(L + BOFF + row * 64 + blk * 8);
      }
    __builtin_amdgcn_s_setprio(1);
    #pragma unroll
    for (int ks = 0; ks < 2; ++ks)
      #pragma unroll
      for (int mf = 0; mf < 4; ++mf)
        #pragma unroll
        for (int nf = 0; nf < 4; ++nf)
          acc[mf][nf] = __builtin_amdgcn_mfma_f32_16x16x32_f16(a[mf][ks], b[nf][ks],
                                                               acc[mf][nf], 0, 0, 0);
    __builtin_amdgcn_s_setprio(0);
  }
  #pragma unroll
  for (int mf = 0; mf < 4; ++mf)
    #pragma unroll
    for (int nf = 0; nf < 4; ++nf) {
      int col = n0 + wn * 64 + nf * 16 + (lane & 15);
      if (col < N) {
        #pragma unroll
        for (int j = 0; j < 4; ++j) {
          long long row = m0 + wm * 64 + mf * 16 + (lane >> 4) * 4 + j;
          C[row * (long long)ldc + col] = acc[mf][nf][j];
        }
      }
    }
}

// ---------------- host launch ----------------

extern "C" void kernel_launch(void* const* d_in, const int* in_sizes, int n_in,
                              void* d_out, int out_size, void* d_ws, size_t ws_size,
                              hipStream_t stream) {
  (void)in_sizes; (void)n_in; (void)out_size; (void)ws_size;
  const int*   idx   = (const int*)d_in[0];
  const float* wte   = (const float*)d_in[1];
  const float* wqkv  = (const float*)d_in[2];
  const float* qnw   = (const float*)d_in[3];
  const float* knw   = (const float*)d_in[4];
  const float* oproj = (const float*)d_in[5];
  const float* ffnw  = (const float*)d_in[6];
  const float* gatew = (const float*)d_in[7];
  const float* w13   = (const float*)d_in[8];
  const float* w2p   = (const float*)d_in[9];
  const float* lnf   = (const float*)d_in[10];
  float* out = (float*)d_out;

  char* base = (char*)d_ws;
  size_t off = 0;
  auto alloc = [&](size_t bytes) -> char* {
    off = (off + 255) & ~(size_t)255;
    char* p = base + off; off += bytes; return p;
  };
  float* x     = (float*)alloc((size_t)Ntok * 768 * 4);
  float* qkv   = (float*)alloc((size_t)Ntok * 2304 * 4);
  float* hbuf  = (float*)alloc((size_t)Ntok * 768 * 4);
  float* ffn   = (float*)alloc((size_t)Ntok * 768 * 4);
  unsigned short* x16   = (unsigned short*)alloc((size_t)Ntok * 1536 * 2);
  unsigned short* yfl16 = (unsigned short*)alloc((size_t)Ntok * 1536 * 2);
  unsigned short* qr16  = (unsigned short*)alloc((size_t)24 * 1024 * 128 * 2);
  unsigned short* kr16  = (unsigned short*)alloc((size_t)24 * 1024 * 128 * 2);
  unsigned short* vr16  = (unsigned short*)alloc((size_t)24 * 64 * 2048 * 2);
  unsigned short* xb16  = (unsigned short*)alloc((size_t)Ec * CAPPc * 1536 * 2);
  unsigned short* wo16  = (unsigned short*)alloc((size_t)768 * 1536 * 2);
  unsigned short* xf16  = (unsigned short*)alloc((size_t)Ntok * 768 * 2);
  char* spb = alloc((size_t)24 * 1024 * 1024 * 4);           // scratch region
  float* yexp = (float*)spb;                                 // [0, 9.4M)
  unsigned short* act16 = (unsigned short*)(spb + 50331648); // [50.3M, 75.5M)
  unsigned short* wq16  = (unsigned short*)(spb + 75497472); // [75.5M, 82.6M)
  unsigned short* w13_16 = (unsigned short*)alloc((size_t)Ec * 4096 * 1536 * 2); // 100.66MB
  unsigned short* wt16   = w13_16;                           // alias (used after)
  unsigned short* w2_16  = (unsigned short*)alloc((size_t)Ec * 768 * 4096 * 2);  // 50.3MB
  int* top    = (int*)alloc(Ntok * 4);
  int* rankb  = (int*)alloc(Ntok * 4);
  int* cnt    = (int*)alloc(Lc * Ec * 4);
  float* psum = (float*)alloc(Lc * Ec * 4);
  float* z2   = (float*)alloc(Lc * 4);

  embed_k<<<Ntok, 192, 0, stream>>>(idx, wte, x, x16, psum, z2);

  for (int l = 0; l < Lc; ++l) {
    split2_wT<1, 0><<<dim3(72, 24, 1), 256, 0, stream>>>(wqkv + (size_t)l * 768 * 2304,
                                                         wq16, 768, 2304, 0, 0);
    split2_wT<1, 0><<<dim3(24, 24, 1), 256, 0, stream>>>(oproj + (size_t)l * 768 * 768,
                                                         wo16, 768, 768, 0, 0);
    if (l == 0) {
      split2_wT<1, 1><<<dim3(128, 24, 8), 256, 0, stream>>>(w13, w13_16,
          768, 4096, (long long)768 * 4096, (long long)4096 * 1536);
      split2_wT<1, 0><<<dim3(24, 64, 8), 256, 0, stream>>>(w2p, w2_16,
          2048, 768, (long long)2048 * 768, (long long)768 * 4096);
    } else {
      split2_wT<0, 1><<<dim3(128, 24, 8), 256, 0, stream>>>(w13 + (size_t)Ec * 768 * 4096,
          w13_16, 768, 4096, (long long)768 * 4096, (long long)4096 * 768);
      split2_wT<0, 0><<<dim3(24, 64, 8), 256, 0, stream>>>(w2p + (size_t)Ec * 2048 * 768,
          w2_16, 2048, 768, (long long)2048 * 768, (long long)768 * 2048);
    }
    // qkv = x @ wqkv[l]
    gemm_h<128, 1, 0, 0, 0><<<288, 256, 0, stream>>>(
        x16, wq16, qkv, nullptr, 2048, 2304, 768, 2304, 16, 18, 0, 0, 1, 0, 0);
    // fused q/k rmsnorm + rope + V transpose
    qk_rope<<<Ntok, 256, 0, stream>>>(qkv, qnw + l * 768, knw + l * 768, qr16, kr16, vr16);
    // fused attention -> yfl16 (split-fp16)
    flash_attn<<<384, 256, 0, stream>>>(qr16, kr16, vr16, yfl16);
    // h = x + y @ o_proj[l]
    gemm_h<64, 1, 1, 0, 0><<<192, 256, 0, stream>>>(
        yfl16, wo16, hbuf, x, 2048, 768, 768, 768, 16, 12, 0, 0, 1, 0, 0);
    rmsnorm_k<<<Ntok, 256, 0, stream>>>(hbuf, 768, ffn, 768, ffnw + l * 768);
    gate_k<<<Ntok / 256, 256, 0, stream>>>(ffn, gatew + (size_t)l * 768 * 8, top,
                                           psum + l * 8, z2 + l);
    route_scan<<<1, 64, 0, stream>>>(top, rankb, cnt + l * 8);
    if (l == 0) {
      scatter_xb<1><<<Ntok, 192, 0, stream>>>(ffn, top, rankb, xb16);
      // act16 = silu(g)*u fused epilogue (g/u-interleaved w13_16)
      gemm_h<128, 1, 0, 0, 1><<<768, 256, 0, stream>>>(
          xb16, w13_16, (float*)act16, nullptr, 384, 4096, 768, 4096, 3, 32,
          (long long)384 * 1536, (long long)4096 * 1536, 1, (long long)384 * 4096, 0);
      gemm_h<64, 1, 0, 0, 0><<<288, 256, 0, stream>>>(
          act16, w2_16, yexp, nullptr, 384, 768, 2048, 768, 3, 12,
          (long long)384 * 4096, (long long)768 * 4096, 1, (long long)384 * 768, 0);
    } else {
      scatter_xb<0><<<Ntok, 192, 0, stream>>>(ffn, top, rankb, xb16);
      gemm_h<128, 0, 0, 0, 2><<<768, 256, 0, stream>>>(
          xb16, w13_16, (float*)act16, nullptr, 384, 4096, 768, 2048, 3, 32,
          (long long)384 * 768, (long long)4096 * 768, 1, (long long)384 * 2048, 0);
      gemm_h<64, 0, 0, 0, 0><<<288, 256, 0, stream>>>(
          act16, w2_16, yexp, nullptr, 384, 768, 2048, 768, 3, 12,
          (long long)384 * 2048, (long long)768 * 2048, 1, (long long)384 * 768, 0);
    }
    gather_add<<<Ntok, 192, 0, stream>>>(hbuf, yexp, top, rankb, x, x16);
  }

  rmsnorm_h<<<Ntok, 256, 0, stream>>>(x, xf16, lnf);
  f2h4<<<(int)(((long long)Vc * 768 / 4 + 255) / 256), 256, 0, stream>>>(
      wte, wt16, (long long)Vc * 768 / 4);
  // logits = xf @ wte^T : 256x128 tile, 3-buffer distance-2 pipelined (R9)
  gemm_logits<<<8 * 393, 512, 0, stream>>>(xf16, wt16, out, 2048, Vc, 768, Vc, 8);
  aux_fin<<<1, 64, 0, stream>>>(psum, cnt, z2, out + LOGITS_N);
}

// Round 12
// 1142.610 us; speedup vs baseline: 1.2339x; 1.0888x over previous
//
// LunarisCodex MoE-GPT forward, MI355X/gfx950. Round 12: logits m-tile-per-XCD
// grid (A-panel pinned in each XCD L2; FETCH -110MB), wave-per-token gate with
// fused ffn-rmsnorm (+rs[] for scatter), f2h4+ln_f merged, aux folded in logits.
#include <hip/hip_runtime.h>

typedef __attribute__((ext_vector_type(8))) _Float16 half8;
typedef __attribute__((ext_vector_type(4))) float f32x4;

constexpr int Bc = 2, Tc = 1024, Dc = 768, NHc = 12, HDc = 64;
constexpr int Vc = 50257, Lc = 2, Ec = 8, Hc = 2048;
constexpr int Ntok = Bc * Tc;            // 2048
constexpr int CAPc = 320, CAPPc = 384;   // capacity, padded rows per expert
constexpr long long LOGITS_N = (long long)Bc * Tc * Vc;  // 102926336

typedef const __attribute__((address_space(1))) unsigned int* gas_t;
typedef __attribute__((address_space(3))) unsigned int* las_t;
__device__ __forceinline__ void gload16(const void* g, void* l) {
  __builtin_amdgcn_global_load_lds((gas_t)g, (las_t)l, 16, 0, 0);
}

__device__ __forceinline__ void splitf16(float a, unsigned short& h, unsigned short& l) {
  _Float16 hh = (_Float16)a;                       // RNE
  _Float16 ll = (_Float16)(a - (float)hh);
  h = __builtin_bit_cast(unsigned short, hh);
  l = __builtin_bit_cast(unsigned short, ll);
}
__device__ __forceinline__ unsigned short f16o(float a) {
  _Float16 hh = (_Float16)a;
  return __builtin_bit_cast(unsigned short, hh);
}

// ---------------- small kernels ----------------

// embed: x (f32) + x16 (split-fp16 [hi768|lo768]); block 0 also zeroes psum/z2
__global__ void embed_k(const int* __restrict__ idx, const float* __restrict__ wte,
                        float* __restrict__ x, unsigned short* __restrict__ x16,
                        float* __restrict__ psum, float* __restrict__ z2) {
  int n = blockIdx.x;
  int t = threadIdx.x;
  if (n == 0) {
    if (t < Lc * Ec) psum[t] = 0.f;
    if (t >= 32 && t < 32 + Lc) z2[t - 32] = 0.f;
  }
  long long v = idx[n];
  const float4* src = (const float4*)(wte + v * 768);
  float4* dst = (float4*)(x + (long long)n * 768);
  if (t < 192) {
    float4 val = src[t];
    dst[t] = val;
    ushort4 h, l;
    splitf16(val.x, h.x, l.x); splitf16(val.y, h.y, l.y);
    splitf16(val.z, h.z, l.z); splitf16(val.w, h.w, l.w);
    unsigned short* d = x16 + (long long)n * 1536 + t * 4;
    *(ushort4*)d = h;
    *(ushort4*)(d + 768) = l;
  }
}

// merged: blocks [0,2048) = ln_f rmsnorm -> fp16; blocks >= 2048 = wte f32->fp16
__global__ void __launch_bounds__(256) final_prep(const float* __restrict__ x,
    const float* __restrict__ lnw, unsigned short* __restrict__ xf,
    const float* __restrict__ wte, unsigned short* __restrict__ wt) {
  int tid = threadIdx.x;
  if (blockIdx.x < Ntok) {
    long long n = blockIdx.x;
    const float* xr = x + n * 768;
    unsigned short* yr = xf + n * 768;
    float s = 0.f;
    for (int i = tid; i < 768; i += 256) { float v = xr[i]; s += v * v; }
    #pragma unroll
    for (int o = 32; o; o >>= 1) s += __shfl_down(s, o);
    __shared__ float red[4];
    __shared__ float bs;
    if ((tid & 63) == 0) red[tid >> 6] = s;
    __syncthreads();
    if (tid == 0) bs = rsqrtf((red[0] + red[1] + red[2] + red[3]) / 768.0f + 1e-5f);
    __syncthreads();
    float sc = bs;
    for (int i = tid; i < 768; i += 256) yr[i] = f16o(xr[i] * sc * lnw[i]);
  } else {
    long long i = (long long)(blockIdx.x - Ntok) * 256 + tid;
    const long long n4 = (long long)Vc * 768 / 4;
    if (i >= n4) return;
    float4 v = ((const float4*)wte)[i];
    ushort4 o;
    o.x = f16o(v.x); o.y = f16o(v.y); o.z = f16o(v.z); o.w = f16o(v.w);
    ((ushort4*)wt)[i] = o;
  }
}

// f32 weights (K,N) -> fp16 transposed. SP=1: (N,2K) [hi|lo]; SP=0: (N,K).
// ILV=1: dst row remapped for g/u interleave: n' = (h>>4)*32 + is_u*16 + (h&15).
template <int SP, int ILV>
__global__ void __launch_bounds__(256) split2_wT(const float* __restrict__ src,
    unsigned short* __restrict__ dst, int K, int N, long long sS, long long sD) {
  __shared__ float t[32][33];
  int z = blockIdx.z;
  src += (long long)z * sS;
  dst += (long long)z * sD;
  int n0 = blockIdx.x * 32, k0 = blockIdx.y * 32;
  int tid = threadIdx.x;
  int r = tid >> 3, c4 = (tid & 7) * 4;
  float4 v = *(const float4*)(src + (long long)(k0 + r) * N + n0 + c4);
  t[r][c4 + 0] = v.x; t[r][c4 + 1] = v.y; t[r][c4 + 2] = v.z; t[r][c4 + 3] = v.w;
  __syncthreads();
  int n = tid >> 3, kq = (tid & 7) * 4;
  ushort4 h, l;
  splitf16(t[kq + 0][n], h.x, l.x);
  splitf16(t[kq + 1][n], h.y, l.y);
  splitf16(t[kq + 2][n], h.z, l.z);
  splitf16(t[kq + 3][n], h.w, l.w);
  const int lda = SP ? 2 * K : K;
  int nd = n0 + n;
  if (ILV) {
    int hh = nd & 2047, iu = nd >> 11;
    nd = ((hh >> 4) << 5) + (iu << 4) + (hh & 15);
  }
  unsigned short* d = dst + (long long)nd * lda + k0 + kq;
  *(ushort4*)d = h;
  if (SP) *(ushort4*)(d + K) = l;
}

// fused q/k rmsnorm + RoPE + V transpose. One block per token.
__global__ void __launch_bounds__(256) qk_rope(const float* __restrict__ qkv,
    const float* __restrict__ qnw, const float* __restrict__ knw,
    unsigned short* __restrict__ qr, unsigned short* __restrict__ kr,
    unsigned short* __restrict__ vr) {
  int n = blockIdx.x;
  int t = n & 1023, b = n >> 10;
  const float* row = qkv + (long long)n * 2304;
  int tid = threadIdx.x;
  float sq = 0.f, sk = 0.f;
  for (int i = tid; i < 768; i += 256) {
    float q = row[i]; sq += q * q;
    float k = row[768 + i]; sk += k * k;
  }
  #pragma unroll
  for (int o = 32; o; o >>= 1) { sq += __shfl_down(sq, o); sk += __shfl_down(sk, o); }
  __shared__ float redq[4], redk[4];
  __shared__ float bq, bk;
  if ((tid & 63) == 0) { redq[tid >> 6] = sq; redk[tid >> 6] = sk; }
  __syncthreads();
  if (tid == 0) {
    bq = rsqrtf((redq[0] + redq[1] + redq[2] + redq[3]) / 768.0f + 1e-5f);
    bk = rsqrtf((redk[0] + redk[1] + redk[2] + redk[3]) / 768.0f + 1e-5f);
  }
  __syncthreads();
  float nq = bq, nk = bk;
  for (int i = tid; i < 384; i += 256) {
    int hh = i >> 5, j = i & 31;
    int c = hh * 64 + 2 * j;
    float ang = (float)t * powf(10000.0f, -((float)j * (1.0f / 32.0f)));
    float cs = cosf(ang), sn = sinf(ang);
    int z = b * 12 + hh;
    long long qb = ((long long)z * 1024 + t) * 128 + 2 * j;
    unsigned short h0, l0, h1, l1;
    float q0 = row[c] * nq * qnw[c], q1 = row[c + 1] * nq * qnw[c + 1];
    splitf16(q0 * cs - q1 * sn, h0, l0);
    splitf16(q0 * sn + q1 * cs, h1, l1);
    *(unsigned int*)&qr[qb] = (unsigned)h0 | ((unsigned)h1 << 16);
    *(unsigned int*)&qr[qb + 64] = (unsigned)l0 | ((unsigned)l1 << 16);
    float k0 = row[768 + c] * nk * knw[c], k1 = row[768 + c + 1] * nk * knw[c + 1];
    splitf16(k0 * cs - k1 * sn, h0, l0);
    splitf16(k0 * sn + k1 * cs, h1, l1);
    *(unsigned int*)&kr[qb] = (unsigned)h0 | ((unsigned)h1 << 16);
    *(unsigned int*)&kr[qb + 64] = (unsigned)l0 | ((unsigned)l1 << 16);
    splitf16(row[1536 + c], h0, l0);
    splitf16(row[1536 + c + 1], h1, l1);
    long long vb = ((long long)z * 64 + 2 * j) * 2048 + t;
    vr[vb] = h0; vr[vb + 1024] = l0;
    vr[vb + 2048] = h1; vr[vb + 3072] = l1;
  }
}

// ---------------- fused flash attention ----------------
__global__ void __launch_bounds__(256) flash_attn(
    const unsigned short* __restrict__ qr, const unsigned short* __restrict__ kr,
    const unsigned short* __restrict__ vr, unsigned short* __restrict__ yout) {
  __shared__ __align__(16) unsigned short Ph[4][16][72];
  __shared__ __align__(16) unsigned short Pl[4][16][72];
  int bid = blockIdx.x;
  int z = bid >> 4;
  int qt = 15 - (bid & 15);          // heavy tiles first (load balance)
  int b = z / 12, h = z % 12;
  int q0 = qt * 64;
  int wave = threadIdx.x >> 6, lane = threadIdx.x & 63;
  int lr = lane & 15, lg = lane >> 4;
  int qw = q0 + wave * 16;           // this wave's 16 q rows
  half8 af[2][2];
  const unsigned short* qbase = qr + ((long long)z * 1024 + qw + lr) * 128;
  #pragma unroll
  for (int ks = 0; ks < 2; ++ks)
    #pragma unroll
    for (int p = 0; p < 2; ++p)
      af[ks][p] = *(const half8*)(qbase + p * 64 + ks * 32 + lg * 8);
  f32x4 accy[4];
  #pragma unroll
  for (int df = 0; df < 4; ++df) accy[df] = (f32x4){0.f, 0.f, 0.f, 0.f};
  float mrun[4] = {-3.4e38f, -3.4e38f, -3.4e38f, -3.4e38f};
  float srun[4] = {0.f, 0.f, 0.f, 0.f};
  for (int kt = 0; kt <= qt; ++kt) {
    int kv0 = kt * 64;
    f32x4 s[4];
    #pragma unroll
    for (int nf = 0; nf < 4; ++nf) s[nf] = (f32x4){0.f, 0.f, 0.f, 0.f};
    const unsigned short* kbase = kr + ((long long)z * 1024 + kv0 + lr) * 128;
    #pragma unroll
    for (int nf = 0; nf < 4; ++nf) {
      const unsigned short* kb = kbase + nf * 16 * 128;
      #pragma unroll
      for (int ks = 0; ks < 2; ++ks) {
        half8 bh = *(const half8*)(kb + ks * 32 + lg * 8);
        half8 bl = *(const half8*)(kb + 64 + ks * 32 + lg * 8);
        s[nf] = __builtin_amdgcn_mfma_f32_16x16x32_f16(af[ks][0], bh, s[nf], 0, 0, 0);
        s[nf] = __builtin_amdgcn_mfma_f32_16x16x32_f16(af[ks][1], bh, s[nf], 0, 0, 0);
        s[nf] = __builtin_amdgcn_mfma_f32_16x16x32_f16(af[ks][0], bl, s[nf], 0, 0, 0);
      }
    }
    bool diag = (kt == qt);
    #pragma unroll
    for (int nf = 0; nf < 4; ++nf)
      #pragma unroll
      for (int j = 0; j < 4; ++j) {
        float v = s[nf][j] * 0.125f;
        if (diag && (nf * 16 + lr > wave * 16 + lg * 4 + j)) v = -1e30f;
        s[nf][j] = v;
      }
    #pragma unroll
    for (int j = 0; j < 4; ++j) {
      float tm = fmaxf(fmaxf(s[0][j], s[1][j]), fmaxf(s[2][j], s[3][j]));
      #pragma unroll
      for (int o = 1; o < 16; o <<= 1) tm = fmaxf(tm, __shfl_xor(tm, o));
      float mnew = fmaxf(mrun[j], tm);
      float sc = expf(mrun[j] - mnew);
      float ts = 0.f;
      #pragma unroll
      for (int nf = 0; nf < 4; ++nf) {
        float p = expf(s[nf][j] - mnew);
        ts += p;
        unsigned short ph, pl;
        splitf16(p, ph, pl);
        Ph[wave][lg * 4 + j][nf * 16 + lr] = ph;
        Pl[wave][lg * 4 + j][nf * 16 + lr] = pl;
      }
      #pragma unroll
      for (int o = 1; o < 16; o <<= 1) ts += __shfl_xor(ts, o);
      srun[j] = srun[j] * sc + ts;
      mrun[j] = mnew;
      #pragma unroll
      for (int df = 0; df < 4; ++df) accy[df][j] *= sc;
    }
    #pragma unroll
    for (int ks2 = 0; ks2 < 2; ++ks2) {
      half8 aph = *(const half8*)&Ph[wave][lr][ks2 * 32 + lg * 8];
      half8 apl = *(const half8*)&Pl[wave][lr][ks2 * 32 + lg * 8];
      #pragma unroll
      for (int df = 0; df < 4; ++df) {
        const unsigned short* vb =
            vr + ((long long)z * 64 + df * 16 + lr) * 2048 + kv0 + ks2 * 32 + lg * 8;
        half8 bvh = *(const half8*)vb;
        half8 bvl = *(const half8*)(vb + 1024);
        accy[df] = __builtin_amdgcn_mfma_f32_16x16x32_f16(aph, bvh, accy[df], 0, 0, 0);
        accy[df] = __builtin_amdgcn_mfma_f32_16x16x32_f16(apl, bvh, accy[df], 0, 0, 0);
        accy[df] = __builtin_amdgcn_mfma_f32_16x16x32_f16(aph, bvl, accy[df], 0, 0, 0);
      }
    }
  }
  float inv[4];
  #pragma unroll
  for (int j = 0; j < 4; ++j) inv[j] = 1.0f / srun[j];
  #pragma unroll
  for (int df = 0; df < 4; ++df)
    #pragma unroll
    for (int j = 0; j < 4; ++j) {
      long long tok = (long long)b * 1024 + qw + lg * 4 + j;
      int col = h * 64 + df * 16 + lr;
      unsigned short hh, ll;
      splitf16(accy[df][j] * inv[j], hh, ll);
      yout[tok * 1536 + col] = hh;
      yout[tok * 1536 + 768 + col] = ll;
    }
}

// gate with fused ffn-rmsnorm: wave-per-token (coalesced row reads).
// logits_e = rs * sum_i (h_i*w_i) g[i][e];  rs stored for scatter_xb.
__global__ void __launch_bounds__(256) gate_k(const float* __restrict__ h,
    const float* __restrict__ w, const float* __restrict__ gw,
    int* __restrict__ top, float* __restrict__ rsq,
    float* __restrict__ psum, float* __restrict__ z2) {
  __shared__ float gws[8][772];     // padded: stride 772 % 32 = 4 (bank spread)
  __shared__ float pacc[8];
  __shared__ float zacc;
  int tid = threadIdx.x;
  for (int i = tid; i < 768 * 8; i += 256) {
    int d = i >> 3, e = i & 7;
    gws[e][d] = gw[i];
  }
  if (tid < 8) pacc[tid] = 0.f;
  if (tid == 0) zacc = 0.f;
  __syncthreads();
  int wave = tid >> 6, lane = tid & 63;
  int n = blockIdx.x * 4 + wave;
  const float* row = h + (long long)n * 768;
  float ss = 0.f;
  float l[8] = {0, 0, 0, 0, 0, 0, 0, 0};
  #pragma unroll
  for (int c = 0; c < 3; ++c) {
    int i = c * 256 + lane * 4;
    float4 v = *(const float4*)(row + i);
    ss += v.x * v.x + v.y * v.y + v.z * v.z + v.w * v.w;
    float4 wv = *(const float4*)(w + i);
    float tx = v.x * wv.x, ty = v.y * wv.y, tz = v.z * wv.z, tw = v.w * wv.w;
    #pragma unroll
    for (int e = 0; e < 8; ++e)
      l[e] += tx * gws[e][i] + ty * gws[e][i + 1] + tz * gws[e][i + 2] + tw * gws[e][i + 3];
  }
  #pragma unroll
  for (int o = 32; o; o >>= 1) {
    ss += __shfl_down(ss, o);
    #pragma unroll
    for (int e = 0; e < 8; ++e) l[e] += __shfl_down(l[e], o);
  }
  if (lane == 0) {
    float rs = rsqrtf(ss / 768.0f + 1e-5f);
    rsq[n] = rs;
    #pragma unroll
    for (int e = 0; e < 8; ++e) l[e] *= rs;
    float mx = l[0]; int bi = 0;
    #pragma unroll
    for (int e = 1; e < 8; ++e) if (l[e] > mx) { mx = l[e]; bi = e; }  // first-max
    float p[8]; float se = 0.f;
    #pragma unroll
    for (int e = 0; e < 8; ++e) { p[e] = expf(l[e] - mx); se += p[e]; }
    float z = mx + logf(se);
    top[n] = bi;
    #pragma unroll
    for (int e = 0; e < 8; ++e) atomicAdd(&pacc[e], p[e] / se);
    atomicAdd(&zacc, z * z);
  }
  __syncthreads();
  if (tid < 8) atomicAdd(&psum[tid], pacc[tid]);
  if (tid == 0) atomicAdd(z2, zacc);
}

// single-wave rank scan (matches stable argsort arrival order)
__global__ void route_scan(const int* __restrict__ top, int* __restrict__ rank,
                           int* __restrict__ cnt) {
  int lane = threadIdx.x;
  int c[8] = {0, 0, 0, 0, 0, 0, 0, 0};
  unsigned long long below = (1ull << lane) - 1ull;
  for (int s = 0; s < Ntok / 64; ++s) {
    int n = s * 64 + lane;
    int e = top[n];
    int r = 0;
    #pragma unroll
    for (int q = 0; q < 8; ++q) {
      unsigned long long m = __ballot(e == q);
      if (e == q) r = c[q] + __popcll(m & below);
      c[q] += __popcll(m);
    }
    rank[n] = r;
  }
  #pragma unroll
  for (int q = 0; q < 8; ++q) if (lane == q) cnt[q] = c[q];
}

// scatter with inline rmsnorm: xb = split/single fp16 of h*rs*w.
template <int SP>
__global__ void scatter_xb(const float* __restrict__ h, const float* __restrict__ w,
                           const float* __restrict__ rsq, const int* __restrict__ top,
                           const int* __restrict__ rank, unsigned short* __restrict__ xb) {
  int n = blockIdx.x;
  int r = rank[n];
  if (r >= CAPc) return;
  int e = top[n];
  float rs = rsq[n];
  int t = threadIdx.x;
  if (t >= 192) return;
  float4 v = ((const float4*)(h + (long long)n * 768))[t];
  float4 wv = ((const float4*)w)[t];
  v.x *= rs * wv.x; v.y *= rs * wv.y; v.z *= rs * wv.z; v.w *= rs * wv.w;
  ushort4 hh, ll;
  splitf16(v.x, hh.x, ll.x); splitf16(v.y, hh.y, ll.y);
  splitf16(v.z, hh.z, ll.z); splitf16(v.w, hh.w, ll.w);
  const int lda = SP ? 1536 : 768;
  unsigned short* dst = xb + ((long long)e * CAPPc + r) * lda + t * 4;
  *(ushort4*)dst = hh;
  if (SP) *(ushort4*)(dst + 768) = ll;
}

// h + expert-out -> x (f32) AND x16 (split-fp16) for next layer
__global__ void gather_add(const float* __restrict__ h, const float* __restrict__ yexp,
                           const int* __restrict__ top, const int* __restrict__ rank,
                           float* __restrict__ xo, unsigned short* __restrict__ x16) {
  int n = blockIdx.x;
  int r = rank[n], e = top[n];
  bool kept = r < CAPc;
  int rc = kept ? r : (CAPc - 1);
  const float4* hs = (const float4*)(h + (long long)n * 768);
  const float4* ys = (const float4*)(yexp + ((long long)e * CAPPc + rc) * 768);
  float4* dst = (float4*)(xo + (long long)n * 768);
  int t = threadIdx.x;
  if (t < 192) {
    float4 v = hs[t];
    if (kept) { float4 y = ys[t]; v.x += y.x; v.y += y.y; v.z += y.z; v.w += y.w; }
    dst[t] = v;
    ushort4 hh, ll;
    splitf16(v.x, hh.x, ll.x); splitf16(v.y, hh.y, ll.y);
    splitf16(v.z, hh.z, ll.z); splitf16(v.w, hh.w, ll.w);
    unsigned short* d = x16 + (long long)n * 1536 + t * 4;
    *(ushort4*)d = hh;
    *(ushort4*)(d + 768) = ll;
  }
}

// ---------------- fp16 MFMA GEMM (single-barrier pipelined dbuf) ----------
// C(M,N) f32 [+Add] = A @ Bt^T. SPLIT=1: [hi K|lo K] (lda=2K), 3 MFMA terms per
// 32-k-slice (4 planes). SPLIT=0: lda=K, BK=64 (2 planes).
// SILU: 1 = silu(g)*u -> split-fp16 act (g/u-interleaved B, BN=128); 2 = single.
template <int BN, int SPLIT, int ADD, int NTAIL, int SILU>
__global__ void __launch_bounds__(256) gemm_h(
    const unsigned short* __restrict__ A, const unsigned short* __restrict__ Bt,
    float* __restrict__ C, const float* __restrict__ Add,
    int M, int N, int K, int ldc, int gx, int gy,
    long long sA, long long sB, int zdiv, long long sC1, long long sC2) {
  constexpr int FN = (BN == 128) ? 4 : 2;
  constexpr int APL = 128 * 32;            // A plane (shorts)
  constexpr int BPL = BN * 32;             // B plane (shorts)
  constexpr int BUF = 2 * APL + 2 * BPL;   // Ah|Al|Bh|Bl
  __shared__ __align__(16) unsigned short lds[2][BUF];
  int tot = gridDim.x;
  int lin = blockIdx.x;
  if ((tot & 7) == 0) lin = (lin & 7) * (tot >> 3) + (lin >> 3);  // XCD chunking
  int pz = lin / (gx * gy);
  int r2 = lin - pz * (gx * gy);
  const int m0 = (r2 % gx) * 128, n0 = (r2 / gx) * BN;
  A += (long long)pz * sA;
  Bt += (long long)pz * sB;
  const long long co = (long long)(pz / zdiv) * sC1 + (long long)(pz % zdiv) * sC2;
  const int lda = SPLIT ? 2 * K : K;
  const int NS = SPLIT ? K / 32 : K / 64;
  const int tid = threadIdx.x;
  const int lane = tid & 63, wave = tid >> 6;
  const int wm = (BN == 128) ? (wave >> 1) : (wave & 1);
  const int wn = (BN == 128) ? (wave & 1) : (wave >> 1);
  const int srow = tid >> 2, scol = (tid & 3) * 8;
  const unsigned short* Ar = A + (long long)(m0 + srow) * lda + scol;
  int br0 = n0 + srow;
  if (NTAIL) br0 = min(br0, N - 1);
  const unsigned short* Br = Bt + (long long)br0 * lda + scol;
  int br1 = n0 + srow + 64;
  if (NTAIL) br1 = min(br1, N - 1);
  const unsigned short* Br2 = Bt + (long long)br1 * lda + scol;

  auto STAGE = [&](int buf, int s) {
    const int kh = SPLIT ? s * 32 : s * 64;
    const int kl = SPLIT ? K + s * 32 : s * 64 + 32;
    unsigned short* L = lds[buf];
    gload16(Ar + kh, &L[wave * 512]);
    gload16(Ar + (long long)64 * lda + kh, &L[2048 + wave * 512]);
    gload16(Ar + kl, &L[APL + wave * 512]);
    gload16(Ar + (long long)64 * lda + kl, &L[APL + 2048 + wave * 512]);
    gload16(Br + kh, &L[2 * APL + wave * 512]);
    gload16(Br + kl, &L[2 * APL + BPL + wave * 512]);
    if (BN == 128) {
      gload16(Br2 + kh, &L[2 * APL + 2048 + wave * 512]);
      gload16(Br2 + kl, &L[2 * APL + BPL + 2048 + wave * 512]);
    }
  };

  f32x4 acc[4][FN];
  #pragma unroll
  for (int m = 0; m < 4; ++m)
    #pragma unroll
    for (int n = 0; n < FN; ++n) acc[m][n] = (f32x4){0.f, 0.f, 0.f, 0.f};

  STAGE(0, 0);
  int cur = 0;
  for (int s = 0; s < NS; ++s) {
    asm volatile("s_waitcnt vmcnt(0)" ::: "memory");   // own stage-s loads landed
    __builtin_amdgcn_sched_barrier(0);
    __builtin_amdgcn_s_barrier();   // all waves: stage-s in LDS; prev reads retired
    if (s + 1 < NS) STAGE(cur ^ 1, s + 1);   // overlaps with reads+MFMA below
    const unsigned short* L = lds[cur];
    half8 bfh[FN], bfl[FN];
    #pragma unroll
    for (int n = 0; n < FN; ++n) {
      int bo = (wn * (FN * 16) + n * 16 + (lane & 15)) * 32 + (lane >> 4) * 8;
      bfh[n] = *(const half8*)&L[2 * APL + bo];
      bfl[n] = *(const half8*)&L[2 * APL + BPL + bo];
    }
    __builtin_amdgcn_s_setprio(1);
    #pragma unroll
    for (int m = 0; m < 4; ++m) {
      int ao = (wm * 64 + m * 16 + (lane & 15)) * 32 + (lane >> 4) * 8;
      half8 afh = *(const half8*)&L[ao];
      half8 afl = *(const half8*)&L[APL + ao];
      #pragma unroll
      for (int n = 0; n < FN; ++n) {
        acc[m][n] = __builtin_amdgcn_mfma_f32_16x16x32_f16(afh, bfh[n], acc[m][n], 0, 0, 0);
        if (SPLIT) {
          acc[m][n] = __builtin_amdgcn_mfma_f32_16x16x32_f16(afl, bfh[n], acc[m][n], 0, 0, 0);
          acc[m][n] = __builtin_amdgcn_mfma_f32_16x16x32_f16(afh, bfl[n], acc[m][n], 0, 0, 0);
        } else {
          acc[m][n] = __builtin_amdgcn_mfma_f32_16x16x32_f16(afl, bfl[n], acc[m][n], 0, 0, 0);
        }
      }
    }
    __builtin_amdgcn_s_setprio(0);
    cur ^= 1;
  }
  if constexpr (SILU) {
    unsigned short* act = (unsigned short*)C;
    #pragma unroll
    for (int m = 0; m < 4; ++m)
      #pragma unroll
      for (int p = 0; p < FN / 2; ++p) {
        f32x4 g = acc[m][2 * p], u = acc[m][2 * p + 1];
        int colh = ((n0 + wn * (FN * 16)) >> 1) + p * 16 + (lane & 15);
        #pragma unroll
        for (int j = 0; j < 4; ++j) {
          long long row = m0 + wm * 64 + m * 16 + (lane >> 4) * 4 + j;
          float gv = g[j];
          float a = gv / (1.f + expf(-gv)) * u[j];
          long long o = co + row * ldc + colh;
          if (SILU == 1) {
            unsigned short hh, ll;
            splitf16(a, hh, ll);
            act[o] = hh;
            act[o + 2048] = ll;
          } else {
            act[o] = f16o(a);
          }
        }
      }
  } else {
    #pragma unroll
    for (int m = 0; m < 4; ++m)
      #pragma unroll
      for (int n = 0; n < FN; ++n) {
        int col = n0 + wn * (FN * 16) + n * 16 + (lane & 15);
        if (!NTAIL || col < N) {
          #pragma unroll
          for (int j = 0; j < 4; ++j) {
            long long row = m0 + wm * 64 + m * 16 + (lane >> 4) * 4 + j;
            long long o = co + row * ldc + col;
            float v = acc[m][n][j];
            if (ADD) v += Add[o];
            C[o] = v;
          }
        }
      }
  }
}

// ---------------- logits GEMM: 256x128 tile, 3-buffer distance-2 pipeline ----
// m-tile = XCD chunk (m0 = lin/gyn): each XCD pins its 384KB A-tile in L2;
// B (wte16) streams via L3. Per step: vmcnt(6) -> ONE s_barrier -> STAGE(s+2)
// -> ds_read buf[s%3] -> MFMA. Block 0 also writes aux_total.
__global__ void __launch_bounds__(512) gemm_logits(
    const unsigned short* __restrict__ A, const unsigned short* __restrict__ Bt,
    float* __restrict__ C, int M, int N, int K, int ldc, int gyn,
    const float* __restrict__ psum, const int* __restrict__ cnt,
    const float* __restrict__ z2, float* __restrict__ auxout) {
  constexpr int BUFS = 24576;            // shorts per buffer (48KB)
  constexpr int BOFF = 16384;            // B region offset (shorts)
  __shared__ __align__(16) unsigned short lds[3 * BUFS];   // 144KB
  if (blockIdx.x == 0 && threadIdx.x == 0) {
    float aux = 0.f;
    for (int l = 0; l < Lc; ++l) {
      float bl = 0.f;
      for (int e = 0; e < 8; ++e)
        bl += (psum[l * 8 + e] * (1.0f / 2048.0f)) * ((float)cnt[l * 8 + e] * (1.0f / 2048.0f));
      aux += bl * (0.01f * 8.0f) + (z2[l] * (1.0f / 2048.0f)) * 0.001f;
    }
    auxout[0] = aux;
  }
  int tot = gridDim.x;
  int lin = blockIdx.x;
  if ((tot & 7) == 0) lin = (lin & 7) * (tot >> 3) + (lin >> 3);  // XCD chunking
  const int m0 = (lin / gyn) * 256, n0 = (lin % gyn) * 128;  // m-tile per XCD
  const int tid = threadIdx.x;
  const int lane = tid & 63;
  const int wm = (tid >> 6) >> 1, wn = (tid >> 6) & 1;
  const int NS = K / 64;   // 12

  auto STAGE = [&](int buf, int t) {
    const int k0 = t * 64;
    unsigned short* L = lds + buf * BUFS;
    #pragma unroll
    for (int i = 0; i < 4; ++i) {                     // A: 256x64
      int idx = tid + i * 512;
      int row = idx >> 3, blk = idx & 7;
      gload16(A + (long long)(m0 + row) * K + k0 + ((blk ^ (row & 7)) << 3),
              L + idx * 8);
    }
    #pragma unroll
    for (int i = 0; i < 2; ++i) {                     // B: 128x64
      int idx = tid + i * 512;
      int row = idx >> 3, blk = idx & 7;
      int br = min(n0 + row, N - 1);
      gload16(Bt + (long long)br * K + k0 + ((blk ^ (row & 7)) << 3),
              L + BOFF + idx * 8);
    }
  };

  f32x4 acc[4][4];
  #pragma unroll
  for (int mf = 0; mf < 4; ++mf)
    #pragma unroll
    for (int nf = 0; nf < 4; ++nf) acc[mf][nf] = (f32x4){0.f, 0.f, 0.f, 0.f};

  STAGE(0, 0); STAGE(1, 1);
  for (int s = 0; s < NS; ++s) {
    if (s + 1 < NS) asm volatile("s_waitcnt vmcnt(6)" ::: "memory");
    else            asm volatile("s_waitcnt vmcnt(0)" ::: "memory");
    __builtin_amdgcn_sched_barrier(0);
    __builtin_amdgcn_s_barrier();          // tile s ready; buf[(s+2)%3] released
    if (s + 2 < NS) STAGE((s + 2) % 3, s + 2);   // overlaps with reads+MFMA
    const unsigned short* L = lds + (s % 3) * BUFS;
    half8 a[4][2], b[4][2];
    #pragma unroll
    for (int mf = 0; mf < 4; ++mf)
      #pragma unroll
      for (int ks = 0; ks < 2; ++ks) {
        int row = wm * 64 + mf * 16 + (lane & 15);
        int blk = (ks * 4 + (lane >> 4)) ^ (row & 7);
        a[mf][ks] = *(const half8*)(L + row * 64 + blk * 8);
      }
    #pragma unroll
    for (int nf = 0; nf < 4; ++nf)
      #pragma unroll
      for (int ks = 0; ks < 2; ++ks) {
        int row = wn * 64 + nf * 16 + (lane & 15);
        int blk = (ks * 4 + (lane >> 4)) ^ (row & 7);
        b[nf][ks] = *(const half8*)(L + BOFF + row * 64 + blk * 8);
      }
    __builtin_amdgcn_s_setprio(1);
    #pragma unroll
    for (int ks = 0; ks < 2; ++ks)
      #pragma unroll
      for (int mf = 0; mf < 4; ++mf)
        #pragma unroll
        for (int nf = 0; nf < 4; ++nf)
          acc[mf][nf] = __builtin_amdgcn_mfma_f32_16x16x32_f16(a[mf][ks], b[nf][ks],
                                                               acc[mf][nf], 0, 0, 0);
    __builtin_amdgcn_s_setprio(0);
  }
  #pragma unroll
  for (int mf = 0; mf < 4; ++mf)
    #pragma unroll
    for (int nf = 0; nf < 4; ++nf) {
      int col = n0 + wn * 64 + nf * 16 + (lane & 15);
      if (col < N) {
        #pragma unroll
        for (int j = 0; j < 4; ++j) {
          long long row = m0 + wm * 64 + mf * 16 + (lane >> 4) * 4 + j;
          C[row * (long long)ldc + col] = acc[mf][nf][j];
        }
      }
    }
}

// ---------------- host launch ----------------

extern "C" void kernel_launch(void* const* d_in, const int* in_sizes, int n_in,
                              void* d_out, int out_size, void* d_ws, size_t ws_size,
                              hipStream_t stream) {
  (void)in_sizes; (void)n_in; (void)out_size; (void)ws_size;
  const int*   idx   = (const int*)d_in[0];
  const float* wte   = (const float*)d_in[1];
  const float* wqkv  = (const float*)d_in[2];
  const float* qnw   = (const float*)d_in[3];
  const float* knw   = (const float*)d_in[4];
  const float* oproj = (const float*)d_in[5];
  const float* ffnw  = (const float*)d_in[6];
  const float* gatew = (const float*)d_in[7];
  const float* w13   = (const float*)d_in[8];
  const float* w2p   = (const float*)d_in[9];
  const float* lnf   = (const float*)d_in[10];
  float* out = (float*)d_out;

  char* base = (char*)d_ws;
  size_t off = 0;
  auto alloc = [&](size_t bytes) -> char* {
    off = (off + 255) & ~(size_t)255;
    char* p = base + off; off += bytes; return p;
  };
  float* x     = (float*)alloc((size_t)Ntok * 768 * 4);
  float* qkv   = (float*)alloc((size_t)Ntok * 2304 * 4);
  float* hbuf  = (float*)alloc((size_t)Ntok * 768 * 4);
  unsigned short* x16   = (unsigned short*)alloc((size_t)Ntok * 1536 * 2);
  unsigned short* yfl16 = (unsigned short*)alloc((size_t)Ntok * 1536 * 2);
  unsigned short* qr16  = (unsigned short*)alloc((size_t)24 * 1024 * 128 * 2);
  unsigned short* kr16  = (unsigned short*)alloc((size_t)24 * 1024 * 128 * 2);
  unsigned short* vr16  = (unsigned short*)alloc((size_t)24 * 64 * 2048 * 2);
  unsigned short* xb16  = (unsigned short*)alloc((size_t)Ec * CAPPc * 1536 * 2);
  unsigned short* wo16  = (unsigned short*)alloc((size_t)768 * 1536 * 2);
  unsigned short* xf16  = (unsigned short*)alloc((size_t)Ntok * 768 * 2);
  char* spb = alloc((size_t)24 * 1024 * 1024 * 4);           // scratch region
  float* yexp = (float*)spb;                                 // [0, 9.4M)
  unsigned short* act16 = (unsigned short*)(spb + 50331648); // [50.3M, 75.5M)
  unsigned short* wq16  = (unsigned short*)(spb + 75497472); // [75.5M, 82.6M)
  unsigned short* w13_16 = (unsigned short*)alloc((size_t)Ec * 4096 * 1536 * 2); // 100.66MB
  unsigned short* wt16   = w13_16;                           // alias (used after)
  unsigned short* w2_16  = (unsigned short*)alloc((size_t)Ec * 768 * 4096 * 2);  // 50.3MB
  int* top    = (int*)alloc(Ntok * 4);
  int* rankb  = (int*)alloc(Ntok * 4);
  int* cnt    = (int*)alloc(Lc * Ec * 4);
  float* psum = (float*)alloc(Lc * Ec * 4);
  float* z2   = (float*)alloc(Lc * 4);
  float* rsq  = (float*)alloc(Ntok * 4);

  embed_k<<<Ntok, 192, 0, stream>>>(idx, wte, x, x16, psum, z2);

  for (int l = 0; l < Lc; ++l) {
    split2_wT<1, 0><<<dim3(72, 24, 1), 256, 0, stream>>>(wqkv + (size_t)l * 768 * 2304,
                                                         wq16, 768, 2304, 0, 0);
    split2_wT<1, 0><<<dim3(24, 24, 1), 256, 0, stream>>>(oproj + (size_t)l * 768 * 768,
                                                         wo16, 768, 768, 0, 0);
    if (l == 0) {
      split2_wT<1, 1><<<dim3(128, 24, 8), 256, 0, stream>>>(w13, w13_16,
          768, 4096, (long long)768 * 4096, (long long)4096 * 1536);
      split2_wT<1, 0><<<dim3(24, 64, 8), 256, 0, stream>>>(w2p, w2_16,
          2048, 768, (long long)2048 * 768, (long long)768 * 4096);
    } else {
      split2_wT<0, 1><<<dim3(128, 24, 8), 256, 0, stream>>>(w13 + (size_t)Ec * 768 * 4096,
          w13_16, 768, 4096, (long long)768 * 4096, (long long)4096 * 768);
      split2_wT<0, 0><<<dim3(24, 64, 8), 256, 0, stream>>>(w2p + (size_t)Ec * 2048 * 768,
          w2_16, 2048, 768, (long long)2048 * 768, (long long)768 * 2048);
    }
    // qkv = x @ wqkv[l]
    gemm_h<128, 1, 0, 0, 0><<<288, 256, 0, stream>>>(
        x16, wq16, qkv, nullptr, 2048, 2304, 768, 2304, 16, 18, 0, 0, 1, 0, 0);
    // fused q/k rmsnorm + rope + V transpose
    qk_rope<<<Ntok, 256, 0, stream>>>(qkv, qnw + l * 768, knw + l * 768, qr16, kr16, vr16);
    // fused attention -> yfl16 (split-fp16)
    flash_attn<<<384, 256, 0, stream>>>(qr16, kr16, vr16, yfl16);
    // h = x + y @ o_proj[l]
    gemm_h<64, 1, 1, 0, 0><<<192, 256, 0, stream>>>(
        yfl16, wo16, hbuf, x, 2048, 768, 768, 768, 16, 12, 0, 0, 1, 0, 0);
    // fused ffn-rmsnorm + gate (writes rs[])
    gate_k<<<Ntok / 4, 256, 0, stream>>>(hbuf, ffnw + l * 768,
                                         gatew + (size_t)l * 768 * 8, top, rsq,
                                         psum + l * 8, z2 + l);
    route_scan<<<1, 64, 0, stream>>>(top, rankb, cnt + l * 8);
    if (l == 0) {
      scatter_xb<1><<<Ntok, 192, 0, stream>>>(hbuf, ffnw + l * 768, rsq, top, rankb, xb16);
      gemm_h<128, 1, 0, 0, 1><<<768, 256, 0, stream>>>(
          xb16, w13_16, (float*)act16, nullptr, 384, 4096, 768, 4096, 3, 32,
          (long long)384 * 1536, (long long)4096 * 1536, 1, (long long)384 * 4096, 0);
      gemm_h<64, 1, 0, 0, 0><<<288, 256, 0, stream>>>(
          act16, w2_16, yexp, nullptr, 384, 768, 2048, 768, 3, 12,
          (long long)384 * 4096, (long long)768 * 4096, 1, (long long)384 * 768, 0);
    } else {
      scatter_xb<0><<<Ntok, 192, 0, stream>>>(hbuf, ffnw + l * 768, rsq, top, rankb, xb16);
      gemm_h<128, 0, 0, 0, 2><<<768, 256, 0, stream>>>(
          xb16, w13_16, (float*)act16, nullptr, 384, 4096, 768, 2048, 3, 32,
          (long long)384 * 768, (long long)4096 * 768, 1, (long long)384 * 2048, 0);
      gemm_h<64, 0, 0, 0, 0><<<288, 256, 0, stream>>>(
          act16, w2_16, yexp, nullptr, 384, 768, 2048, 768, 3, 12,
          (long long)384 * 2048, (long long)768 * 2048, 1, (long long)384 * 768, 0);
    }
    gather_add<<<Ntok, 192, 0, stream>>>(hbuf, yexp, top, rankb, x, x16);
  }

  // merged ln_f (blocks < 2048) + wte f32->fp16 (remaining blocks)
  final_prep<<<Ntok + 37694, 256, 0, stream>>>(x, lnf, xf16, wte, wt16);
  // logits = xf @ wte^T : m-tile-per-XCD grid; block 0 writes aux
  gemm_logits<<<8 * 393, 512, 0, stream>>>(xf16, wt16, out, 2048, Vc, 768, Vc, 393,
                                           psum, cnt, z2, out + LOGITS_N);
}

// Round 13
// 1118.311 us; speedup vs baseline: 1.2607x; 1.0217x over previous
//
// LunarisCodex MoE-GPT forward, MI355X/gfx950. Round 13: 256x256 logits tile
// (halved stage traffic + rounds, 2x MFMA per barrier; acc[8][4], 128KB LDS,
// dist-1 single-barrier). Rest identical to R12 (1142us baseline).
#include <hip/hip_runtime.h>

typedef __attribute__((ext_vector_type(8))) _Float16 half8;
typedef __attribute__((ext_vector_type(4))) float f32x4;

constexpr int Bc = 2, Tc = 1024, Dc = 768, NHc = 12, HDc = 64;
constexpr int Vc = 50257, Lc = 2, Ec = 8, Hc = 2048;
constexpr int Ntok = Bc * Tc;            // 2048
constexpr int CAPc = 320, CAPPc = 384;   // capacity, padded rows per expert
constexpr long long LOGITS_N = (long long)Bc * Tc * Vc;  // 102926336

typedef const __attribute__((address_space(1))) unsigned int* gas_t;
typedef __attribute__((address_space(3))) unsigned int* las_t;
__device__ __forceinline__ void gload16(const void* g, void* l) {
  __builtin_amdgcn_global_load_lds((gas_t)g, (las_t)l, 16, 0, 0);
}

__device__ __forceinline__ void splitf16(float a, unsigned short& h, unsigned short& l) {
  _Float16 hh = (_Float16)a;                       // RNE
  _Float16 ll = (_Float16)(a - (float)hh);
  h = __builtin_bit_cast(unsigned short, hh);
  l = __builtin_bit_cast(unsigned short, ll);
}
__device__ __forceinline__ unsigned short f16o(float a) {
  _Float16 hh = (_Float16)a;
  return __builtin_bit_cast(unsigned short, hh);
}

// ---------------- small kernels ----------------

// embed: x (f32) + x16 (split-fp16 [hi768|lo768]); block 0 also zeroes psum/z2
__global__ void embed_k(const int* __restrict__ idx, const float* __restrict__ wte,
                        float* __restrict__ x, unsigned short* __restrict__ x16,
                        float* __restrict__ psum, float* __restrict__ z2) {
  int n = blockIdx.x;
  int t = threadIdx.x;
  if (n == 0) {
    if (t < Lc * Ec) psum[t] = 0.f;
    if (t >= 32 && t < 32 + Lc) z2[t - 32] = 0.f;
  }
  long long v = idx[n];
  const float4* src = (const float4*)(wte + v * 768);
  float4* dst = (float4*)(x + (long long)n * 768);
  if (t < 192) {
    float4 val = src[t];
    dst[t] = val;
    ushort4 h, l;
    splitf16(val.x, h.x, l.x); splitf16(val.y, h.y, l.y);
    splitf16(val.z, h.z, l.z); splitf16(val.w, h.w, l.w);
    unsigned short* d = x16 + (long long)n * 1536 + t * 4;
    *(ushort4*)d = h;
    *(ushort4*)(d + 768) = l;
  }
}

// merged: blocks [0,2048) = ln_f rmsnorm -> fp16; blocks >= 2048 = wte f32->fp16
__global__ void __launch_bounds__(256) final_prep(const float* __restrict__ x,
    const float* __restrict__ lnw, unsigned short* __restrict__ xf,
    const float* __restrict__ wte, unsigned short* __restrict__ wt) {
  int tid = threadIdx.x;
  if (blockIdx.x < Ntok) {
    long long n = blockIdx.x;
    const float* xr = x + n * 768;
    unsigned short* yr = xf + n * 768;
    float s = 0.f;
    for (int i = tid; i < 768; i += 256) { float v = xr[i]; s += v * v; }
    #pragma unroll
    for (int o = 32; o; o >>= 1) s += __shfl_down(s, o);
    __shared__ float red[4];
    __shared__ float bs;
    if ((tid & 63) == 0) red[tid >> 6] = s;
    __syncthreads();
    if (tid == 0) bs = rsqrtf((red[0] + red[1] + red[2] + red[3]) / 768.0f + 1e-5f);
    __syncthreads();
    float sc = bs;
    for (int i = tid; i < 768; i += 256) yr[i] = f16o(xr[i] * sc * lnw[i]);
  } else {
    long long i = (long long)(blockIdx.x - Ntok) * 256 + tid;
    const long long n4 = (long long)Vc * 768 / 4;
    if (i >= n4) return;
    float4 v = ((const float4*)wte)[i];
    ushort4 o;
    o.x = f16o(v.x); o.y = f16o(v.y); o.z = f16o(v.z); o.w = f16o(v.w);
    ((ushort4*)wt)[i] = o;
  }
}

// f32 weights (K,N) -> fp16 transposed. SP=1: (N,2K) [hi|lo]; SP=0: (N,K).
// ILV=1: dst row remapped for g/u interleave: n' = (h>>4)*32 + is_u*16 + (h&15).
template <int SP, int ILV>
__global__ void __launch_bounds__(256) split2_wT(const float* __restrict__ src,
    unsigned short* __restrict__ dst, int K, int N, long long sS, long long sD) {
  __shared__ float t[32][33];
  int z = blockIdx.z;
  src += (long long)z * sS;
  dst += (long long)z * sD;
  int n0 = blockIdx.x * 32, k0 = blockIdx.y * 32;
  int tid = threadIdx.x;
  int r = tid >> 3, c4 = (tid & 7) * 4;
  float4 v = *(const float4*)(src + (long long)(k0 + r) * N + n0 + c4);
  t[r][c4 + 0] = v.x; t[r][c4 + 1] = v.y; t[r][c4 + 2] = v.z; t[r][c4 + 3] = v.w;
  __syncthreads();
  int n = tid >> 3, kq = (tid & 7) * 4;
  ushort4 h, l;
  splitf16(t[kq + 0][n], h.x, l.x);
  splitf16(t[kq + 1][n], h.y, l.y);
  splitf16(t[kq + 2][n], h.z, l.z);
  splitf16(t[kq + 3][n], h.w, l.w);
  const int lda = SP ? 2 * K : K;
  int nd = n0 + n;
  if (ILV) {
    int hh = nd & 2047, iu = nd >> 11;
    nd = ((hh >> 4) << 5) + (iu << 4) + (hh & 15);
  }
  unsigned short* d = dst + (long long)nd * lda + k0 + kq;
  *(ushort4*)d = h;
  if (SP) *(ushort4*)(d + K) = l;
}

// fused q/k rmsnorm + RoPE + V transpose. One block per token.
__global__ void __launch_bounds__(256) qk_rope(const float* __restrict__ qkv,
    const float* __restrict__ qnw, const float* __restrict__ knw,
    unsigned short* __restrict__ qr, unsigned short* __restrict__ kr,
    unsigned short* __restrict__ vr) {
  int n = blockIdx.x;
  int t = n & 1023, b = n >> 10;
  const float* row = qkv + (long long)n * 2304;
  int tid = threadIdx.x;
  float sq = 0.f, sk = 0.f;
  for (int i = tid; i < 768; i += 256) {
    float q = row[i]; sq += q * q;
    float k = row[768 + i]; sk += k * k;
  }
  #pragma unroll
  for (int o = 32; o; o >>= 1) { sq += __shfl_down(sq, o); sk += __shfl_down(sk, o); }
  __shared__ float redq[4], redk[4];
  __shared__ float bq, bk;
  if ((tid & 63) == 0) { redq[tid >> 6] = sq; redk[tid >> 6] = sk; }
  __syncthreads();
  if (tid == 0) {
    bq = rsqrtf((redq[0] + redq[1] + redq[2] + redq[3]) / 768.0f + 1e-5f);
    bk = rsqrtf((redk[0] + redk[1] + redk[2] + redk[3]) / 768.0f + 1e-5f);
  }
  __syncthreads();
  float nq = bq, nk = bk;
  for (int i = tid; i < 384; i += 256) {
    int hh = i >> 5, j = i & 31;
    int c = hh * 64 + 2 * j;
    float ang = (float)t * powf(10000.0f, -((float)j * (1.0f / 32.0f)));
    float cs = cosf(ang), sn = sinf(ang);
    int z = b * 12 + hh;
    long long qb = ((long long)z * 1024 + t) * 128 + 2 * j;
    unsigned short h0, l0, h1, l1;
    float q0 = row[c] * nq * qnw[c], q1 = row[c + 1] * nq * qnw[c + 1];
    splitf16(q0 * cs - q1 * sn, h0, l0);
    splitf16(q0 * sn + q1 * cs, h1, l1);
    *(unsigned int*)&qr[qb] = (unsigned)h0 | ((unsigned)h1 << 16);
    *(unsigned int*)&qr[qb + 64] = (unsigned)l0 | ((unsigned)l1 << 16);
    float k0 = row[768 + c] * nk * knw[c], k1 = row[768 + c + 1] * nk * knw[c + 1];
    splitf16(k0 * cs - k1 * sn, h0, l0);
    splitf16(k0 * sn + k1 * cs, h1, l1);
    *(unsigned int*)&kr[qb] = (unsigned)h0 | ((unsigned)h1 << 16);
    *(unsigned int*)&kr[qb + 64] = (unsigned)l0 | ((unsigned)l1 << 16);
    splitf16(row[1536 + c], h0, l0);
    splitf16(row[1536 + c + 1], h1, l1);
    long long vb = ((long long)z * 64 + 2 * j) * 2048 + t;
    vr[vb] = h0; vr[vb + 1024] = l0;
    vr[vb + 2048] = h1; vr[vb + 3072] = l1;
  }
}

// ---------------- fused flash attention ----------------
__global__ void __launch_bounds__(256) flash_attn(
    const unsigned short* __restrict__ qr, const unsigned short* __restrict__ kr,
    const unsigned short* __restrict__ vr, unsigned short* __restrict__ yout) {
  __shared__ __align__(16) unsigned short Ph[4][16][72];
  __shared__ __align__(16) unsigned short Pl[4][16][72];
  int bid = blockIdx.x;
  int z = bid >> 4;
  int qt = 15 - (bid & 15);          // heavy tiles first (load balance)
  int b = z / 12, h = z % 12;
  int q0 = qt * 64;
  int wave = threadIdx.x >> 6, lane = threadIdx.x & 63;
  int lr = lane & 15, lg = lane >> 4;
  int qw = q0 + wave * 16;           // this wave's 16 q rows
  half8 af[2][2];
  const unsigned short* qbase = qr + ((long long)z * 1024 + qw + lr) * 128;
  #pragma unroll
  for (int ks = 0; ks < 2; ++ks)
    #pragma unroll
    for (int p = 0; p < 2; ++p)
      af[ks][p] = *(const half8*)(qbase + p * 64 + ks * 32 + lg * 8);
  f32x4 accy[4];
  #pragma unroll
  for (int df = 0; df < 4; ++df) accy[df] = (f32x4){0.f, 0.f, 0.f, 0.f};
  float mrun[4] = {-3.4e38f, -3.4e38f, -3.4e38f, -3.4e38f};
  float srun[4] = {0.f, 0.f, 0.f, 0.f};
  for (int kt = 0; kt <= qt; ++kt) {
    int kv0 = kt * 64;
    f32x4 s[4];
    #pragma unroll
    for (int nf = 0; nf < 4; ++nf) s[nf] = (f32x4){0.f, 0.f, 0.f, 0.f};
    const unsigned short* kbase = kr + ((long long)z * 1024 + kv0 + lr) * 128;
    #pragma unroll
    for (int nf = 0; nf < 4; ++nf) {
      const unsigned short* kb = kbase + nf * 16 * 128;
      #pragma unroll
      for (int ks = 0; ks < 2; ++ks) {
        half8 bh = *(const half8*)(kb + ks * 32 + lg * 8);
        half8 bl = *(const half8*)(kb + 64 + ks * 32 + lg * 8);
        s[nf] = __builtin_amdgcn_mfma_f32_16x16x32_f16(af[ks][0], bh, s[nf], 0, 0, 0);
        s[nf] = __builtin_amdgcn_mfma_f32_16x16x32_f16(af[ks][1], bh, s[nf], 0, 0, 0);
        s[nf] = __builtin_amdgcn_mfma_f32_16x16x32_f16(af[ks][0], bl, s[nf], 0, 0, 0);
      }
    }
    bool diag = (kt == qt);
    #pragma unroll
    for (int nf = 0; nf < 4; ++nf)
      #pragma unroll
      for (int j = 0; j < 4; ++j) {
        float v = s[nf][j] * 0.125f;
        if (diag && (nf * 16 + lr > wave * 16 + lg * 4 + j)) v = -1e30f;
        s[nf][j] = v;
      }
    #pragma unroll
    for (int j = 0; j < 4; ++j) {
      float tm = fmaxf(fmaxf(s[0][j], s[1][j]), fmaxf(s[2][j], s[3][j]));
      #pragma unroll
      for (int o = 1; o < 16; o <<= 1) tm = fmaxf(tm, __shfl_xor(tm, o));
      float mnew = fmaxf(mrun[j], tm);
      float sc = expf(mrun[j] - mnew);
      float ts = 0.f;
      #pragma unroll
      for (int nf = 0; nf < 4; ++nf) {
        float p = expf(s[nf][j] - mnew);
        ts += p;
        unsigned short ph, pl;
        splitf16(p, ph, pl);
        Ph[wave][lg * 4 + j][nf * 16 + lr] = ph;
        Pl[wave][lg * 4 + j][nf * 16 + lr] = pl;
      }
      #pragma unroll
      for (int o = 1; o < 16; o <<= 1) ts += __shfl_xor(ts, o);
      srun[j] = srun[j] * sc + ts;
      mrun[j] = mnew;
      #pragma unroll
      for (int df = 0; df < 4; ++df) accy[df][j] *= sc;
    }
    #pragma unroll
    for (int ks2 = 0; ks2 < 2; ++ks2) {
      half8 aph = *(const half8*)&Ph[wave][lr][ks2 * 32 + lg * 8];
      half8 apl = *(const half8*)&Pl[wave][lr][ks2 * 32 + lg * 8];
      #pragma unroll
      for (int df = 0; df < 4; ++df) {
        const unsigned short* vb =
            vr + ((long long)z * 64 + df * 16 + lr) * 2048 + kv0 + ks2 * 32 + lg * 8;
        half8 bvh = *(const half8*)vb;
        half8 bvl = *(const half8*)(vb + 1024);
        accy[df] = __builtin_amdgcn_mfma_f32_16x16x32_f16(aph, bvh, accy[df], 0, 0, 0);
        accy[df] = __builtin_amdgcn_mfma_f32_16x16x32_f16(apl, bvh, accy[df], 0, 0, 0);
        accy[df] = __builtin_amdgcn_mfma_f32_16x16x32_f16(aph, bvl, accy[df], 0, 0, 0);
      }
    }
  }
  float inv[4];
  #pragma unroll
  for (int j = 0; j < 4; ++j) inv[j] = 1.0f / srun[j];
  #pragma unroll
  for (int df = 0; df < 4; ++df)
    #pragma unroll
    for (int j = 0; j < 4; ++j) {
      long long tok = (long long)b * 1024 + qw + lg * 4 + j;
      int col = h * 64 + df * 16 + lr;
      unsigned short hh, ll;
      splitf16(accy[df][j] * inv[j], hh, ll);
      yout[tok * 1536 + col] = hh;
      yout[tok * 1536 + 768 + col] = ll;
    }
}

// gate with fused ffn-rmsnorm: wave-per-token (coalesced row reads).
__global__ void __launch_bounds__(256) gate_k(const float* __restrict__ h,
    const float* __restrict__ w, const float* __restrict__ gw,
    int* __restrict__ top, float* __restrict__ rsq,
    float* __restrict__ psum, float* __restrict__ z2) {
  __shared__ float gws[8][772];
  __shared__ float pacc[8];
  __shared__ float zacc;
  int tid = threadIdx.x;
  for (int i = tid; i < 768 * 8; i += 256) {
    int d = i >> 3, e = i & 7;
    gws[e][d] = gw[i];
  }
  if (tid < 8) pacc[tid] = 0.f;
  if (tid == 0) zacc = 0.f;
  __syncthreads();
  int wave = tid >> 6, lane = tid & 63;
  int n = blockIdx.x * 4 + wave;
  const float* row = h + (long long)n * 768;
  float ss = 0.f;
  float l[8] = {0, 0, 0, 0, 0, 0, 0, 0};
  #pragma unroll
  for (int c = 0; c < 3; ++c) {
    int i = c * 256 + lane * 4;
    float4 v = *(const float4*)(row + i);
    ss += v.x * v.x + v.y * v.y + v.z * v.z + v.w * v.w;
    float4 wv = *(const float4*)(w + i);
    float tx = v.x * wv.x, ty = v.y * wv.y, tz = v.z * wv.z, tw = v.w * wv.w;
    #pragma unroll
    for (int e = 0; e < 8; ++e)
      l[e] += tx * gws[e][i] + ty * gws[e][i + 1] + tz * gws[e][i + 2] + tw * gws[e][i + 3];
  }
  #pragma unroll
  for (int o = 32; o; o >>= 1) {
    ss += __shfl_down(ss, o);
    #pragma unroll
    for (int e = 0; e < 8; ++e) l[e] += __shfl_down(l[e], o);
  }
  if (lane == 0) {
    float rs = rsqrtf(ss / 768.0f + 1e-5f);
    rsq[n] = rs;
    #pragma unroll
    for (int e = 0; e < 8; ++e) l[e] *= rs;
    float mx = l[0]; int bi = 0;
    #pragma unroll
    for (int e = 1; e < 8; ++e) if (l[e] > mx) { mx = l[e]; bi = e; }  // first-max
    float p[8]; float se = 0.f;
    #pragma unroll
    for (int e = 0; e < 8; ++e) { p[e] = expf(l[e] - mx); se += p[e]; }
    float z = mx + logf(se);
    top[n] = bi;
    #pragma unroll
    for (int e = 0; e < 8; ++e) atomicAdd(&pacc[e], p[e] / se);
    atomicAdd(&zacc, z * z);
  }
  __syncthreads();
  if (tid < 8) atomicAdd(&psum[tid], pacc[tid]);
  if (tid == 0) atomicAdd(z2, zacc);
}

// single-wave rank scan (matches stable argsort arrival order)
__global__ void route_scan(const int* __restrict__ top, int* __restrict__ rank,
                           int* __restrict__ cnt) {
  int lane = threadIdx.x;
  int c[8] = {0, 0, 0, 0, 0, 0, 0, 0};
  unsigned long long below = (1ull << lane) - 1ull;
  for (int s = 0; s < Ntok / 64; ++s) {
    int n = s * 64 + lane;
    int e = top[n];
    int r = 0;
    #pragma unroll
    for (int q = 0; q < 8; ++q) {
      unsigned long long m = __ballot(e == q);
      if (e == q) r = c[q] + __popcll(m & below);
      c[q] += __popcll(m);
    }
    rank[n] = r;
  }
  #pragma unroll
  for (int q = 0; q < 8; ++q) if (lane == q) cnt[q] = c[q];
}

// scatter with inline rmsnorm: xb = split/single fp16 of h*rs*w.
template <int SP>
__global__ void scatter_xb(const float* __restrict__ h, const float* __restrict__ w,
                           const float* __restrict__ rsq, const int* __restrict__ top,
                           const int* __restrict__ rank, unsigned short* __restrict__ xb) {
  int n = blockIdx.x;
  int r = rank[n];
  if (r >= CAPc) return;
  int e = top[n];
  float rs = rsq[n];
  int t = threadIdx.x;
  if (t >= 192) return;
  float4 v = ((const float4*)(h + (long long)n * 768))[t];
  float4 wv = ((const float4*)w)[t];
  v.x *= rs * wv.x; v.y *= rs * wv.y; v.z *= rs * wv.z; v.w *= rs * wv.w;
  ushort4 hh, ll;
  splitf16(v.x, hh.x, ll.x); splitf16(v.y, hh.y, ll.y);
  splitf16(v.z, hh.z, ll.z); splitf16(v.w, hh.w, ll.w);
  const int lda = SP ? 1536 : 768;
  unsigned short* dst = xb + ((long long)e * CAPPc + r) * lda + t * 4;
  *(ushort4*)dst = hh;
  if (SP) *(ushort4*)(dst + 768) = ll;
}

// h + expert-out -> x (f32) AND x16 (split-fp16) for next layer
__global__ void gather_add(const float* __restrict__ h, const float* __restrict__ yexp,
                           const int* __restrict__ top, const int* __restrict__ rank,
                           float* __restrict__ xo, unsigned short* __restrict__ x16) {
  int n = blockIdx.x;
  int r = rank[n], e = top[n];
  bool kept = r < CAPc;
  int rc = kept ? r : (CAPc - 1);
  const float4* hs = (const float4*)(h + (long long)n * 768);
  const float4* ys = (const float4*)(yexp + ((long long)e * CAPPc + rc) * 768);
  float4* dst = (float4*)(xo + (long long)n * 768);
  int t = threadIdx.x;
  if (t < 192) {
    float4 v = hs[t];
    if (kept) { float4 y = ys[t]; v.x += y.x; v.y += y.y; v.z += y.z; v.w += y.w; }
    dst[t] = v;
    ushort4 hh, ll;
    splitf16(v.x, hh.x, ll.x); splitf16(v.y, hh.y, ll.y);
    splitf16(v.z, hh.z, ll.z); splitf16(v.w, hh.w, ll.w);
    unsigned short* d = x16 + (long long)n * 1536 + t * 4;
    *(ushort4*)d = hh;
    *(ushort4*)(d + 768) = ll;
  }
}

// ---------------- fp16 MFMA GEMM (single-barrier pipelined dbuf) ----------
template <int BN, int SPLIT, int ADD, int NTAIL, int SILU>
__global__ void __launch_bounds__(256) gemm_h(
    const unsigned short* __restrict__ A, const unsigned short* __restrict__ Bt,
    float* __restrict__ C, const float* __restrict__ Add,
    int M, int N, int K, int ldc, int gx, int gy,
    long long sA, long long sB, int zdiv, long long sC1, long long sC2) {
  constexpr int FN = (BN == 128) ? 4 : 2;
  constexpr int APL = 128 * 32;            // A plane (shorts)
  constexpr int BPL = BN * 32;             // B plane (shorts)
  constexpr int BUF = 2 * APL + 2 * BPL;   // Ah|Al|Bh|Bl
  __shared__ __align__(16) unsigned short lds[2][BUF];
  int tot = gridDim.x;
  int lin = blockIdx.x;
  if ((tot & 7) == 0) lin = (lin & 7) * (tot >> 3) + (lin >> 3);  // XCD chunking
  int pz = lin / (gx * gy);
  int r2 = lin - pz * (gx * gy);
  const int m0 = (r2 % gx) * 128, n0 = (r2 / gx) * BN;
  A += (long long)pz * sA;
  Bt += (long long)pz * sB;
  const long long co = (long long)(pz / zdiv) * sC1 + (long long)(pz % zdiv) * sC2;
  const int lda = SPLIT ? 2 * K : K;
  const int NS = SPLIT ? K / 32 : K / 64;
  const int tid = threadIdx.x;
  const int lane = tid & 63, wave = tid >> 6;
  const int wm = (BN == 128) ? (wave >> 1) : (wave & 1);
  const int wn = (BN == 128) ? (wave & 1) : (wave >> 1);
  const int srow = tid >> 2, scol = (tid & 3) * 8;
  const unsigned short* Ar = A + (long long)(m0 + srow) * lda + scol;
  int br0 = n0 + srow;
  if (NTAIL) br0 = min(br0, N - 1);
  const unsigned short* Br = Bt + (long long)br0 * lda + scol;
  int br1 = n0 + srow + 64;
  if (NTAIL) br1 = min(br1, N - 1);
  const unsigned short* Br2 = Bt + (long long)br1 * lda + scol;

  auto STAGE = [&](int buf, int s) {
    const int kh = SPLIT ? s * 32 : s * 64;
    const int kl = SPLIT ? K + s * 32 : s * 64 + 32;
    unsigned short* L = lds[buf];
    gload16(Ar + kh, &L[wave * 512]);
    gload16(Ar + (long long)64 * lda + kh, &L[2048 + wave * 512]);
    gload16(Ar + kl, &L[APL + wave * 512]);
    gload16(Ar + (long long)64 * lda + kl, &L[APL + 2048 + wave * 512]);
    gload16(Br + kh, &L[2 * APL + wave * 512]);
    gload16(Br + kl, &L[2 * APL + BPL + wave * 512]);
    if (BN == 128) {
      gload16(Br2 + kh, &L[2 * APL + 2048 + wave * 512]);
      gload16(Br2 + kl, &L[2 * APL + BPL + 2048 + wave * 512]);
    }
  };

  f32x4 acc[4][FN];
  #pragma unroll
  for (int m = 0; m < 4; ++m)
    #pragma unroll
    for (int n = 0; n < FN; ++n) acc[m][n] = (f32x4){0.f, 0.f, 0.f, 0.f};

  STAGE(0, 0);
  int cur = 0;
  for (int s = 0; s < NS; ++s) {
    asm volatile("s_waitcnt vmcnt(0)" ::: "memory");   // own stage-s loads landed
    __builtin_amdgcn_sched_barrier(0);
    __builtin_amdgcn_s_barrier();   // all waves: stage-s in LDS; prev reads retired
    if (s + 1 < NS) STAGE(cur ^ 1, s + 1);   // overlaps with reads+MFMA below
    const unsigned short* L = lds[cur];
    half8 bfh[FN], bfl[FN];
    #pragma unroll
    for (int n = 0; n < FN; ++n) {
      int bo = (wn * (FN * 16) + n * 16 + (lane & 15)) * 32 + (lane >> 4) * 8;
      bfh[n] = *(const half8*)&L[2 * APL + bo];
      bfl[n] = *(const half8*)&L[2 * APL + BPL + bo];
    }
    __builtin_amdgcn_s_setprio(1);
    #pragma unroll
    for (int m = 0; m < 4; ++m) {
      int ao = (wm * 64 + m * 16 + (lane & 15)) * 32 + (lane >> 4) * 8;
      half8 afh = *(const half8*)&L[ao];
      half8 afl = *(const half8*)&L[APL + ao];
      #pragma unroll
      for (int n = 0; n < FN; ++n) {
        acc[m][n] = __builtin_amdgcn_mfma_f32_16x16x32_f16(afh, bfh[n], acc[m][n], 0, 0, 0);
        if (SPLIT) {
          acc[m][n] = __builtin_amdgcn_mfma_f32_16x16x32_f16(afl, bfh[n], acc[m][n], 0, 0, 0);
          acc[m][n] = __builtin_amdgcn_mfma_f32_16x16x32_f16(afh, bfl[n], acc[m][n], 0, 0, 0);
        } else {
          acc[m][n] = __builtin_amdgcn_mfma_f32_16x16x32_f16(afl, bfl[n], acc[m][n], 0, 0, 0);
        }
      }
    }
    __builtin_amdgcn_s_setprio(0);
    cur ^= 1;
  }
  if constexpr (SILU) {
    unsigned short* act = (unsigned short*)C;
    #pragma unroll
    for (int m = 0; m < 4; ++m)
      #pragma unroll
      for (int p = 0; p < FN / 2; ++p) {
        f32x4 g = acc[m][2 * p], u = acc[m][2 * p + 1];
        int colh = ((n0 + wn * (FN * 16)) >> 1) + p * 16 + (lane & 15);
        #pragma unroll
        for (int j = 0; j < 4; ++j) {
          long long row = m0 + wm * 64 + m * 16 + (lane >> 4) * 4 + j;
          float gv = g[j];
          float a = gv / (1.f + expf(-gv)) * u[j];
          long long o = co + row * ldc + colh;
          if (SILU == 1) {
            unsigned short hh, ll;
            splitf16(a, hh, ll);
            act[o] = hh;
            act[o + 2048] = ll;
          } else {
            act[o] = f16o(a);
          }
        }
      }
  } else {
    #pragma unroll
    for (int m = 0; m < 4; ++m)
      #pragma unroll
      for (int n = 0; n < FN; ++n) {
        int col = n0 + wn * (FN * 16) + n * 16 + (lane & 15);
        if (!NTAIL || col < N) {
          #pragma unroll
          for (int j = 0; j < 4; ++j) {
            long long row = m0 + wm * 64 + m * 16 + (lane >> 4) * 4 + j;
            long long o = co + row * ldc + col;
            float v = acc[m][n][j];
            if (ADD) v += Add[o];
            C[o] = v;
          }
        }
      }
  }
}

// ---------------- logits GEMM: 256x256 tile, 2-buffer single-barrier ----
// 8 waves (2m x 4n), acc[8][4]; buf = A 256x64 (32KB) + B 256x64 (32KB); 128KB.
// Halves stage traffic/round-count vs 256x128; 64 MFMA per wave per barrier.
// Swizzle: 16B-block ^= row&7 on gload source AND ds_read (rule #21).
// m-tile per XCD (m0 = lin/gyn). Block 0 writes aux_total.
__global__ void __launch_bounds__(512) gemm_logits(
    const unsigned short* __restrict__ A, const unsigned short* __restrict__ Bt,
    float* __restrict__ C, int M, int N, int K, int ldc, int gyn,
    const float* __restrict__ psum, const int* __restrict__ cnt,
    const float* __restrict__ z2, float* __restrict__ auxout) {
  constexpr int BUFS = 32768;            // shorts per buffer (64KB)
  constexpr int BOFF = 16384;            // B region offset (shorts)
  __shared__ __align__(16) unsigned short lds[2][BUFS];   // 128KB
  if (blockIdx.x == 0 && threadIdx.x == 0) {
    float aux = 0.f;
    for (int l = 0; l < Lc; ++l) {
      float bl = 0.f;
      for (int e = 0; e < 8; ++e)
        bl += (psum[l * 8 + e] * (1.0f / 2048.0f)) * ((float)cnt[l * 8 + e] * (1.0f / 2048.0f));
      aux += bl * (0.01f * 8.0f) + (z2[l] * (1.0f / 2048.0f)) * 0.001f;
    }
    auxout[0] = aux;
  }
  int tot = gridDim.x;
  int lin = blockIdx.x;
  if ((tot & 7) == 0) lin = (lin & 7) * (tot >> 3) + (lin >> 3);  // XCD chunking
  const int m0 = (lin / gyn) * 256, n0 = (lin % gyn) * 256;  // m-tile per XCD
  const int tid = threadIdx.x;
  const int lane = tid & 63;
  const int wm = (tid >> 6) >> 2, wn = (tid >> 6) & 3;   // 2m x 4n
  const int NS = K / 64;   // 12

  auto STAGE = [&](int buf, int t) {
    const int k0 = t * 64;
    unsigned short* L = lds[buf];
    #pragma unroll
    for (int i = 0; i < 4; ++i) {                     // A: 256x64
      int idx = tid + i * 512;
      int row = idx >> 3, blk = idx & 7;
      gload16(A + (long long)(m0 + row) * K + k0 + ((blk ^ (row & 7)) << 3),
              L + idx * 8);
    }
    #pragma unroll
    for (int i = 0; i < 4; ++i) {                     // B: 256x64
      int idx = tid + i * 512;
      int row = idx >> 3, blk = idx & 7;
      int br = min(n0 + row, N - 1);
      gload16(Bt + (long long)br * K + k0 + ((blk ^ (row & 7)) << 3),
              L + BOFF + idx * 8);
    }
  };

  f32x4 acc[8][4];
  #pragma unroll
  for (int mf = 0; mf < 8; ++mf)
    #pragma unroll
    for (int nf = 0; nf < 4; ++nf) acc[mf][nf] = (f32x4){0.f, 0.f, 0.f, 0.f};

  STAGE(0, 0);
  int cur = 0;
  for (int s = 0; s < NS; ++s) {
    asm volatile("s_waitcnt vmcnt(0)" ::: "memory");   // own stage-s loads landed
    __builtin_amdgcn_sched_barrier(0);
    __builtin_amdgcn_s_barrier();        // tile s in LDS; prev reads retired
    if (s + 1 < NS) STAGE(cur ^ 1, s + 1);   // overlaps with reads+MFMA
    const unsigned short* L = lds[cur];
    half8 b[4][2];
    #pragma unroll
    for (int nf = 0; nf < 4; ++nf)
      #pragma unroll
      for (int ks = 0; ks < 2; ++ks) {
        int row = wn * 64 + nf * 16 + (lane & 15);
        int blk = (ks * 4 + (lane >> 4)) ^ (row & 7);
        b[nf][ks] = *(const half8*)(L + BOFF + row * 64 + blk * 8);
      }
    __builtin_amdgcn_s_setprio(1);
    #pragma unroll
    for (int mf = 0; mf < 8; ++mf) {
      int arow = wm * 128 + mf * 16 + (lane & 15);
      #pragma unroll
      for (int ks = 0; ks < 2; ++ks) {
        int blk = (ks * 4 + (lane >> 4)) ^ (arow & 7);
        half8 a = *(const half8*)(L + arow * 64 + blk * 8);
        #pragma unroll
        for (int nf = 0; nf < 4; ++nf)
          acc[mf][nf] = __builtin_amdgcn_mfma_f32_16x16x32_f16(a, b[nf][ks],
                                                               acc[mf][nf], 0, 0, 0);
      }
    }
    __builtin_amdgcn_s_setprio(0);
    cur ^= 1;
  }
  #pragma unroll
  for (int mf = 0; mf < 8; ++mf)
    #pragma unroll
    for (int nf = 0; nf < 4; ++nf) {
      int col = n0 + wn * 64 + nf * 16 + (lane & 15);
      if (col < N) {
        #pragma unroll
        for (int j = 0; j < 4; ++j) {
          long long row = m0 + wm * 128 + mf * 16 + (lane >> 4) * 4 + j;
          C[row * (long long)ldc + col] = acc[mf][nf][j];
        }
      }
    }
}

// ---------------- host launch ----------------

extern "C" void kernel_launch(void* const* d_in, const int* in_sizes, int n_in,
                              void* d_out, int out_size, void* d_ws, size_t ws_size,
                              hipStream_t stream) {
  (void)in_sizes; (void)n_in; (void)out_size; (void)ws_size;
  const int*   idx   = (const int*)d_in[0];
  const float* wte   = (const float*)d_in[1];
  const float* wqkv  = (const float*)d_in[2];
  const float* qnw   = (const float*)d_in[3];
  const float* knw   = (const float*)d_in[4];
  const float* oproj = (const float*)d_in[5];
  const float* ffnw  = (const float*)d_in[6];
  const float* gatew = (const float*)d_in[7];
  const float* w13   = (const float*)d_in[8];
  const float* w2p   = (const float*)d_in[9];
  const float* lnf   = (const float*)d_in[10];
  float* out = (float*)d_out;

  char* base = (char*)d_ws;
  size_t off = 0;
  auto alloc = [&](size_t bytes) -> char* {
    off = (off + 255) & ~(size_t)255;
    char* p = base + off; off += bytes; return p;
  };
  float* x     = (float*)alloc((size_t)Ntok * 768 * 4);
  float* qkv   = (float*)alloc((size_t)Ntok * 2304 * 4);
  float* hbuf  = (float*)alloc((size_t)Ntok * 768 * 4);
  unsigned short* x16   = (unsigned short*)alloc((size_t)Ntok * 1536 * 2);
  unsigned short* yfl16 = (unsigned short*)alloc((size_t)Ntok * 1536 * 2);
  unsigned short* qr16  = (unsigned short*)alloc((size_t)24 * 1024 * 128 * 2);
  unsigned short* kr16  = (unsigned short*)alloc((size_t)24 * 1024 * 128 * 2);
  unsigned short* vr16  = (unsigned short*)alloc((size_t)24 * 64 * 2048 * 2);
  unsigned short* xb16  = (unsigned short*)alloc((size_t)Ec * CAPPc * 1536 * 2);
  unsigned short* wo16  = (unsigned short*)alloc((size_t)768 * 1536 * 2);
  unsigned short* xf16  = (unsigned short*)alloc((size_t)Ntok * 768 * 2);
  char* spb = alloc((size_t)24 * 1024 * 1024 * 4);           // scratch region
  float* yexp = (float*)spb;                                 // [0, 9.4M)
  unsigned short* act16 = (unsigned short*)(spb + 50331648); // [50.3M, 75.5M)
  unsigned short* wq16  = (unsigned short*)(spb + 75497472); // [75.5M, 82.6M)
  unsigned short* w13_16 = (unsigned short*)alloc((size_t)Ec * 4096 * 1536 * 2); // 100.66MB
  unsigned short* wt16   = w13_16;                           // alias (used after)
  unsigned short* w2_16  = (unsigned short*)alloc((size_t)Ec * 768 * 4096 * 2);  // 50.3MB
  int* top    = (int*)alloc(Ntok * 4);
  int* rankb  = (int*)alloc(Ntok * 4);
  int* cnt    = (int*)alloc(Lc * Ec * 4);
  float* psum = (float*)alloc(Lc * Ec * 4);
  float* z2   = (float*)alloc(Lc * 4);
  float* rsq  = (float*)alloc(Ntok * 4);

  embed_k<<<Ntok, 192, 0, stream>>>(idx, wte, x, x16, psum, z2);

  for (int l = 0; l < Lc; ++l) {
    split2_wT<1, 0><<<dim3(72, 24, 1), 256, 0, stream>>>(wqkv + (size_t)l * 768 * 2304,
                                                         wq16, 768, 2304, 0, 0);
    split2_wT<1, 0><<<dim3(24, 24, 1), 256, 0, stream>>>(oproj + (size_t)l * 768 * 768,
                                                         wo16, 768, 768, 0, 0);
    if (l == 0) {
      split2_wT<1, 1><<<dim3(128, 24, 8), 256, 0, stream>>>(w13, w13_16,
          768, 4096, (long long)768 * 4096, (long long)4096 * 1536);
      split2_wT<1, 0><<<dim3(24, 64, 8), 256, 0, stream>>>(w2p, w2_16,
          2048, 768, (long long)2048 * 768, (long long)768 * 4096);
    } else {
      split2_wT<0, 1><<<dim3(128, 24, 8), 256, 0, stream>>>(w13 + (size_t)Ec * 768 * 4096,
          w13_16, 768, 4096, (long long)768 * 4096, (long long)4096 * 768);
      split2_wT<0, 0><<<dim3(24, 64, 8), 256, 0, stream>>>(w2p + (size_t)Ec * 2048 * 768,
          w2_16, 2048, 768, (long long)2048 * 768, (long long)768 * 2048);
    }
    // qkv = x @ wqkv[l]
    gemm_h<128, 1, 0, 0, 0><<<288, 256, 0, stream>>>(
        x16, wq16, qkv, nullptr, 2048, 2304, 768, 2304, 16, 18, 0, 0, 1, 0, 0);
    // fused q/k rmsnorm + rope + V transpose
    qk_rope<<<Ntok, 256, 0, stream>>>(qkv, qnw + l * 768, knw + l * 768, qr16, kr16, vr16);
    // fused attention -> yfl16 (split-fp16)
    flash_attn<<<384, 256, 0, stream>>>(qr16, kr16, vr16, yfl16);
    // h = x + y @ o_proj[l]
    gemm_h<64, 1, 1, 0, 0><<<192, 256, 0, stream>>>(
        yfl16, wo16, hbuf, x, 2048, 768, 768, 768, 16, 12, 0, 0, 1, 0, 0);
    // fused ffn-rmsnorm + gate (writes rs[])
    gate_k<<<Ntok / 4, 256, 0, stream>>>(hbuf, ffnw + l * 768,
                                         gatew + (size_t)l * 768 * 8, top, rsq,
                                         psum + l * 8, z2 + l);
    route_scan<<<1, 64, 0, stream>>>(top, rankb, cnt + l * 8);
    if (l == 0) {
      scatter_xb<1><<<Ntok, 192, 0, stream>>>(hbuf, ffnw + l * 768, rsq, top, rankb, xb16);
      gemm_h<128, 1, 0, 0, 1><<<768, 256, 0, stream>>>(
          xb16, w13_16, (float*)act16, nullptr, 384, 4096, 768, 4096, 3, 32,
          (long long)384 * 1536, (long long)4096 * 1536, 1, (long long)384 * 4096, 0);
      gemm_h<64, 1, 0, 0, 0><<<288, 256, 0, stream>>>(
          act16, w2_16, yexp, nullptr, 384, 768, 2048, 768, 3, 12,
          (long long)384 * 4096, (long long)768 * 4096, 1, (long long)384 * 768, 0);
    } else {
      scatter_xb<0><<<Ntok, 192, 0, stream>>>(hbuf, ffnw + l * 768, rsq, top, rankb, xb16);
      gemm_h<128, 0, 0, 0, 2><<<768, 256, 0, stream>>>(
          xb16, w13_16, (float*)act16, nullptr, 384, 4096, 768, 2048, 3, 32,
          (long long)384 * 768, (long long)4096 * 768, 1, (long long)384 * 2048, 0);
      gemm_h<64, 0, 0, 0, 0><<<288, 256, 0, stream>>>(
          act16, w2_16, yexp, nullptr, 384, 768, 2048, 768, 3, 12,
          (long long)384 * 2048, (long long)768 * 2048, 1, (long long)384 * 768, 0);
    }
    gather_add<<<Ntok, 192, 0, stream>>>(hbuf, yexp, top, rankb, x, x16);
  }

  // merged ln_f (blocks < 2048) + wte f32->fp16 (remaining blocks)
  final_prep<<<Ntok + 37694, 256, 0, stream>>>(x, lnf, xf16, wte, wt16);
  // logits = xf @ wte^T : 256x256 tile, m-tile-per-XCD; grid 8 x 197
  gemm_logits<<<8 * 197, 512, 0, stream>>>(xf16, wt16, out, 2048, Vc, 768, Vc, 197,
                                           psum, cnt, z2, out + LOGITS_N);
}